// Round 1
// baseline (687.527 us; speedup 1.0000x reference)
//
#include <hip/hip_runtime.h>
#include <math.h>

// ---------------------------------------------------------------------------
// GCN forward: 2 sparse aggregations (CSR, built on-device) + small dense GEMMs
// with fused head weights. All fp32.
// ---------------------------------------------------------------------------

static __device__ __forceinline__ float wave_max64(float v) {
#pragma unroll
  for (int o = 32; o; o >>= 1) v = fmaxf(v, __shfl_xor(v, o, 64));
  return v;
}
static __device__ __forceinline__ float wave_sum64(float v) {
#pragma unroll
  for (int o = 32; o; o >>= 1) v += __shfl_xor(v, o, 64);
  return v;
}

// ---- zero int buffer ------------------------------------------------------
__global__ void k_zero(int* __restrict__ p, int n) {
  int i = blockIdx.x * blockDim.x + threadIdx.x;
  if (i < n) p[i] = 0;
}

// ---- degree count (in-degree over dst) ------------------------------------
__global__ void k_deg(const int* __restrict__ dst, int E, int* __restrict__ deg) {
  int e = blockIdx.x * blockDim.x + threadIdx.x;
  if (e < E) atomicAdd(&deg[dst[e]], 1);
}

// ---- 3-kernel exclusive scan over N ints (grid <= 256 blocks of 256) ------
__global__ void k_scan1(const int* __restrict__ deg, int n,
                        int* __restrict__ excl, int* __restrict__ bsum) {
  __shared__ int sm[256];
  int i = blockIdx.x * 256 + threadIdx.x;
  int v = (i < n) ? deg[i] : 0;
  sm[threadIdx.x] = v;
  __syncthreads();
#pragma unroll
  for (int o = 1; o < 256; o <<= 1) {
    int t = (threadIdx.x >= o) ? sm[threadIdx.x - o] : 0;
    __syncthreads();
    sm[threadIdx.x] += t;
    __syncthreads();
  }
  if (i < n) excl[i] = sm[threadIdx.x] - v;
  if (threadIdx.x == 255) bsum[blockIdx.x] = sm[255];
}

__global__ void k_scan2(int* __restrict__ bsum, int nb) {
  __shared__ int sm[256];
  int v = (threadIdx.x < nb) ? bsum[threadIdx.x] : 0;
  sm[threadIdx.x] = v;
  __syncthreads();
#pragma unroll
  for (int o = 1; o < 256; o <<= 1) {
    int t = (threadIdx.x >= o) ? sm[threadIdx.x - o] : 0;
    __syncthreads();
    sm[threadIdx.x] += t;
    __syncthreads();
  }
  if (threadIdx.x < nb) bsum[threadIdx.x] = sm[threadIdx.x] - v;  // exclusive
}

__global__ void k_finalize(int* __restrict__ row_off, const int* __restrict__ bsum,
                           const int* __restrict__ deg, int* __restrict__ cursor,
                           float* __restrict__ dinv, int n) {
  int i = blockIdx.x * 256 + threadIdx.x;
  if (i < n) {
    int ro = row_off[i] + bsum[blockIdx.x];
    row_off[i] = ro;
    cursor[i] = ro;
    dinv[i] = rsqrtf((float)(deg[i] + 1));  // +1 self-loop
  }
}

// ---- CSR fill -------------------------------------------------------------
__global__ void k_fill(const int* __restrict__ src, const int* __restrict__ dst,
                       int E, int* __restrict__ cursor, int* __restrict__ csr) {
  int e = blockIdx.x * blockDim.x + threadIdx.x;
  if (e < E) {
    int d = dst[e];
    int p = atomicAdd(&cursor[d], 1);
    csr[p] = src[e];
  }
}

// ---- aggregation: out[i] = dinv[i]*( sum_s X[s]*dinv[s] + X[i]*dinv[i] ) --
// one wave per node; lane holds 2 consecutive floats of the 128-wide row.
__global__ __launch_bounds__(256) void k_agg(
    const float* __restrict__ X, float* __restrict__ out,
    const int* __restrict__ row_off, const int* __restrict__ deg,
    const int* __restrict__ csr, const float* __restrict__ dinv, int n) {
  int wave = threadIdx.x >> 6;
  int lane = threadIdx.x & 63;
  int i = blockIdx.x * 4 + wave;
  if (i >= n) return;
  int start = row_off[i];
  int cnt = deg[i];
  const float2* Xf2 = reinterpret_cast<const float2*>(X);
  float ax = 0.f, ay = 0.f;
  for (int j = 0; j < cnt; ++j) {
    int s = csr[start + j];
    float ds = dinv[s];
    float2 v = Xf2[(size_t)s * 64 + lane];
    ax += v.x * ds;
    ay += v.y * ds;
  }
  float di = dinv[i];
  float2 vs = Xf2[(size_t)i * 64 + lane];
  ax = (ax + vs.x * di) * di;
  ay = (ay + vs.y * di) * di;
  float2 r;
  r.x = ax;
  r.y = ay;
  reinterpret_cast<float2*>(out)[(size_t)i * 64 + lane] = r;
}

// ---- dense 128x128 GEMM (+bias, optional relu): out = act(A @ W + b) ------
// block 256: 32 rows x 32 col-groups (4 cols each). W + 32 A-rows in LDS.
__global__ __launch_bounds__(256) void k_gemm128(
    const float* __restrict__ A, const float* __restrict__ W,
    const float* __restrict__ bias, float* __restrict__ out, int n, int dorelu) {
  __shared__ float sW[128 * 128];
  __shared__ float sA[32][128];
  for (int t = threadIdx.x; t < 128 * 32; t += 256)
    reinterpret_cast<float4*>(sW)[t] = reinterpret_cast<const float4*>(W)[t];
  int rowBase = blockIdx.x * 32;
  for (int t = threadIdx.x; t < 32 * 32; t += 256) {
    int r = t >> 5, c4 = t & 31;
    int gr = rowBase + r;
    float4 v = (gr < n) ? reinterpret_cast<const float4*>(A)[(size_t)gr * 32 + c4]
                        : make_float4(0.f, 0.f, 0.f, 0.f);
    reinterpret_cast<float4*>(&sA[0][0])[t] = v;
  }
  __syncthreads();
  int cg = threadIdx.x & 31, rg = threadIdx.x >> 5;
  float acc[4][4] = {};  // [ri][comp]
  for (int k = 0; k < 128; ++k) {
    float4 w = reinterpret_cast<const float4*>(sW)[k * 32 + cg];
#pragma unroll
    for (int ri = 0; ri < 4; ++ri) {
      float a = sA[rg * 4 + ri][k];
      acc[ri][0] += a * w.x;
      acc[ri][1] += a * w.y;
      acc[ri][2] += a * w.z;
      acc[ri][3] += a * w.w;
    }
  }
  float4 b4 = reinterpret_cast<const float4*>(bias)[cg];
#pragma unroll
  for (int ri = 0; ri < 4; ++ri) {
    int r = rowBase + rg * 4 + ri;
    if (r < n) {
      float4 o;
      o.x = acc[ri][0] + b4.x;
      o.y = acc[ri][1] + b4.y;
      o.z = acc[ri][2] + b4.z;
      o.w = acc[ri][3] + b4.w;
      if (dorelu) {
        o.x = fmaxf(o.x, 0.f);
        o.y = fmaxf(o.y, 0.f);
        o.z = fmaxf(o.z, 0.f);
        o.w = fmaxf(o.w, 0.f);
      }
      reinterpret_cast<float4*>(out)[(size_t)r * 32 + cg] = o;
    }
  }
}

// ---- fuse head weights: Wf[128][256] cols: [0,20)=Wt@Wct, [20,50)=Ws@Wcs,
// [50,250)=Wa@Wca, [250,256)=0. bf likewise (b1st@W2nd + b2nd). -------------
__global__ void k_fuse(const float* __restrict__ Wt, const float* __restrict__ bt,
                       const float* __restrict__ Wct, const float* __restrict__ bct,
                       const float* __restrict__ Ws, const float* __restrict__ bs,
                       const float* __restrict__ Wcs, const float* __restrict__ bcs,
                       const float* __restrict__ Wa, const float* __restrict__ ba,
                       const float* __restrict__ Wca, const float* __restrict__ bca,
                       float* __restrict__ Wf, float* __restrict__ bf) {
  int c = blockIdx.x;   // 0..255
  int i = threadIdx.x;  // 0..127
  float acc = 0.f, bacc = 0.f;
  if (c < 20) {
    for (int k = 0; k < 20; ++k) {
      float w2 = Wct[k * 20 + c];
      acc += Wt[i * 20 + k] * w2;
      bacc += bt[k] * w2;
    }
    bacc += bct[c];
  } else if (c < 50) {
    int cc = c - 20;
    for (int k = 0; k < 30; ++k) {
      float w2 = Wcs[k * 30 + cc];
      acc += Ws[i * 30 + k] * w2;
      bacc += bs[k] * w2;
    }
    bacc += bcs[cc];
  } else if (c < 250) {
    int cc = c - 50;
    for (int k = 0; k < 200; ++k) {
      float w2 = Wca[k * 200 + cc];
      acc += Wa[i * 200 + k] * w2;
      bacc += ba[k] * w2;
    }
    bacc += bca[cc];
  }
  Wf[i * 256 + c] = acc;
  if (i == 0) bf[c] = bacc;
}

// ---- heads: z = aggH @ Wf + bf ; per-segment softmax ; scatter to out -----
// block 256 = 4 waves; wave handles 4 rows; lane holds cols 4l..4l+3.
__global__ __launch_bounds__(256) void k_heads(
    const float* __restrict__ AH, const float* __restrict__ Wf,
    const float* __restrict__ bf, float* __restrict__ out, int n) {
  __shared__ float sW[128 * 256];
  __shared__ float sb[256];
  __shared__ float sA[16][128];
  for (int t = threadIdx.x; t < 128 * 64; t += 256)
    reinterpret_cast<float4*>(sW)[t] = reinterpret_cast<const float4*>(Wf)[t];
  if (threadIdx.x < 64)
    reinterpret_cast<float4*>(sb)[threadIdx.x] =
        reinterpret_cast<const float4*>(bf)[threadIdx.x];
  int rowBase = blockIdx.x * 16;
  for (int t = threadIdx.x; t < 16 * 32; t += 256) {
    int r = t >> 5, c4 = t & 31;
    int gr = rowBase + r;
    float4 v = (gr < n) ? reinterpret_cast<const float4*>(AH)[(size_t)gr * 32 + c4]
                        : make_float4(0.f, 0.f, 0.f, 0.f);
    reinterpret_cast<float4*>(&sA[0][0])[t] = v;
  }
  __syncthreads();
  int wave = threadIdx.x >> 6, lane = threadIdx.x & 63;
  int rl0 = wave * 4;
  float acc[4][4];  // [q][ri]
#pragma unroll
  for (int q = 0; q < 4; ++q)
#pragma unroll
    for (int ri = 0; ri < 4; ++ri) acc[q][ri] = 0.f;
  for (int k = 0; k < 128; ++k) {
    float4 w = reinterpret_cast<const float4*>(sW)[k * 64 + lane];
    float a0 = sA[rl0 + 0][k], a1 = sA[rl0 + 1][k], a2 = sA[rl0 + 2][k],
          a3 = sA[rl0 + 3][k];
    acc[0][0] += a0 * w.x; acc[1][0] += a0 * w.y; acc[2][0] += a0 * w.z; acc[3][0] += a0 * w.w;
    acc[0][1] += a1 * w.x; acc[1][1] += a1 * w.y; acc[2][1] += a1 * w.z; acc[3][1] += a1 * w.w;
    acc[0][2] += a2 * w.x; acc[1][2] += a2 * w.y; acc[2][2] += a2 * w.z; acc[3][2] += a2 * w.w;
    acc[0][3] += a3 * w.x; acc[1][3] += a3 * w.y; acc[2][3] += a3 * w.z; acc[3][3] += a3 * w.w;
  }
  float4 b4 = reinterpret_cast<const float4*>(sb)[lane];
  float bq[4] = {b4.x, b4.y, b4.z, b4.w};
  float* outT = out;
  float* outS = out + (size_t)n * 20;
  float* outA = out + (size_t)n * 65;
  int c0 = lane * 4;
#pragma unroll
  for (int ri = 0; ri < 4; ++ri) {
    int r = rowBase + rl0 + ri;
    if (r >= n) continue;  // wave-uniform
    float v[4];
#pragma unroll
    for (int q = 0; q < 4; ++q) v[q] = acc[q][ri] + bq[q];
    float e[4];
    // ---- type head: cols [0,20)
    {
      float m = -INFINITY;
#pragma unroll
      for (int q = 0; q < 4; ++q) { int c = c0 + q; if (c < 20) m = fmaxf(m, v[q]); }
      m = wave_max64(m);
      float s = 0.f;
#pragma unroll
      for (int q = 0; q < 4; ++q) {
        int c = c0 + q;
        e[q] = (c < 20) ? expf(v[q] - m) : 0.f;
        s += e[q];
      }
      s = wave_sum64(s);
      float inv = 1.f / s;
#pragma unroll
      for (int q = 0; q < 4; ++q) { int c = c0 + q; if (c < 20) outT[(size_t)r * 20 + c] = e[q] * inv; }
    }
    // ---- school head: cols [20,50)
    {
      float m = -INFINITY;
#pragma unroll
      for (int q = 0; q < 4; ++q) { int c = c0 + q; if (c >= 20 && c < 50) m = fmaxf(m, v[q]); }
      m = wave_max64(m);
      float s = 0.f;
#pragma unroll
      for (int q = 0; q < 4; ++q) {
        int c = c0 + q;
        e[q] = (c >= 20 && c < 50) ? expf(v[q] - m) : 0.f;
        s += e[q];
      }
      s = wave_sum64(s);
      float inv = 1.f / s;
#pragma unroll
      for (int q = 0; q < 4; ++q) { int c = c0 + q; if (c >= 20 && c < 50) outS[(size_t)r * 30 + (c - 20)] = e[q] * inv; }
    }
    // ---- author head: cols [50,250)
    {
      float m = -INFINITY;
#pragma unroll
      for (int q = 0; q < 4; ++q) { int c = c0 + q; if (c >= 50 && c < 250) m = fmaxf(m, v[q]); }
      m = wave_max64(m);
      float s = 0.f;
#pragma unroll
      for (int q = 0; q < 4; ++q) {
        int c = c0 + q;
        e[q] = (c >= 50 && c < 250) ? expf(v[q] - m) : 0.f;
        s += e[q];
      }
      s = wave_sum64(s);
      float inv = 1.f / s;
#pragma unroll
      for (int q = 0; q < 4; ++q) { int c = c0 + q; if (c >= 50 && c < 250) outA[(size_t)r * 200 + (c - 50)] = e[q] * inv; }
    }
  }
}

// ---- time head: softmax(x0 @ Wtf + btf) -----------------------------------
// block 256 = 16 rows x 16 lanes (col j, j<15 active).
__global__ __launch_bounds__(256) void k_time(
    const float* __restrict__ x0, const float* __restrict__ Wtf,
    const float* __restrict__ btf, float* __restrict__ outT, int n) {
  __shared__ float sW[128][16];
  __shared__ float sb[16];
  for (int t = threadIdx.x; t < 128 * 16; t += 256) {
    int k = t >> 4, j = t & 15;
    sW[k][j] = (j < 15) ? Wtf[k * 15 + j] : 0.f;
  }
  if (threadIdx.x < 16) sb[threadIdx.x] = (threadIdx.x < 15) ? btf[threadIdx.x] : 0.f;
  __syncthreads();
  int j = threadIdx.x & 15;
  int rl = threadIdx.x >> 4;
  int r = blockIdx.x * 16 + rl;
  if (r >= n) return;
  float acc = sb[j];
  const float4* xr = reinterpret_cast<const float4*>(x0 + (size_t)r * 128);
  for (int k4 = 0; k4 < 32; ++k4) {
    float4 xv = xr[k4];
    acc += xv.x * sW[k4 * 4 + 0][j] + xv.y * sW[k4 * 4 + 1][j] +
           xv.z * sW[k4 * 4 + 2][j] + xv.w * sW[k4 * 4 + 3][j];
  }
  float m = (j < 15) ? acc : -INFINITY;
#pragma unroll
  for (int o = 8; o; o >>= 1) m = fmaxf(m, __shfl_xor(m, o, 16));
  float e = (j < 15) ? expf(acc - m) : 0.f;
  float s = e;
#pragma unroll
  for (int o = 8; o; o >>= 1) s += __shfl_xor(s, o, 16);
  if (j < 15) outT[(size_t)r * 15 + j] = e / s;
}

// ---------------------------------------------------------------------------
extern "C" void kernel_launch(void* const* d_in, const int* in_sizes, int n_in,
                              void* d_out, int out_size, void* d_ws, size_t ws_size,
                              hipStream_t stream) {
  const float* x0 = (const float*)d_in[0];
  const int* ei = (const int*)d_in[1];
  const float* W1 = (const float*)d_in[2];
  const float* b1 = (const float*)d_in[3];
  const float* Wt = (const float*)d_in[4];
  const float* bt = (const float*)d_in[5];
  const float* Ws = (const float*)d_in[6];
  const float* bs = (const float*)d_in[7];
  const float* Wa = (const float*)d_in[8];
  const float* ba = (const float*)d_in[9];
  const float* Wct = (const float*)d_in[10];
  const float* bct = (const float*)d_in[11];
  const float* Wcs = (const float*)d_in[12];
  const float* bcs = (const float*)d_in[13];
  const float* Wtf = (const float*)d_in[14];
  const float* btf = (const float*)d_in[15];
  const float* Wca = (const float*)d_in[16];
  const float* bca = (const float*)d_in[17];
  (void)n_in; (void)out_size; (void)ws_size;

  int N = in_sizes[0] / 128;
  int E = in_sizes[1] / 2;
  float* out = (float*)d_out;

  char* ws = (char*)d_ws;
  size_t off = 0;
  auto alloc = [&](size_t bytes) -> void* {
    void* p = ws + off;
    off = (off + bytes + 255) & ~(size_t)255;
    return p;
  };
  int* deg = (int*)alloc((size_t)N * 4);
  int* row_off = (int*)alloc((size_t)N * 4);
  int* bsum = (int*)alloc(256 * 4);
  int* cursor = (int*)alloc((size_t)N * 4);
  float* dinv = (float*)alloc((size_t)N * 4);
  int* csr = (int*)alloc((size_t)E * 4);
  float* Wf = (float*)alloc((size_t)128 * 256 * 4);
  float* bf = (float*)alloc(256 * 4);
  float* A = (float*)alloc((size_t)N * 128 * 4);
  float* B = (float*)alloc((size_t)N * 128 * 4);

  const int* srcp = ei;
  const int* dstp = ei + E;
  int gE = (E + 255) / 256;
  int gN = (N + 255) / 256;  // 196 <= 256, required by k_scan2

  k_zero<<<gN, 256, 0, stream>>>(deg, N);
  k_deg<<<gE, 256, 0, stream>>>(dstp, E, deg);
  k_scan1<<<gN, 256, 0, stream>>>(deg, N, row_off, bsum);
  k_scan2<<<1, 256, 0, stream>>>(bsum, gN);
  k_finalize<<<gN, 256, 0, stream>>>(row_off, bsum, deg, cursor, dinv, N);
  k_fill<<<gE, 256, 0, stream>>>(srcp, dstp, E, cursor, csr);
  k_agg<<<(N + 3) / 4, 256, 0, stream>>>(x0, A, row_off, deg, csr, dinv, N);
  k_gemm128<<<(N + 31) / 32, 256, 0, stream>>>(A, W1, b1, B, N, 1);
  k_agg<<<(N + 3) / 4, 256, 0, stream>>>(B, A, row_off, deg, csr, dinv, N);
  k_fuse<<<256, 128, 0, stream>>>(Wt, bt, Wct, bct, Ws, bs, Wcs, bcs, Wa, ba, Wca,
                                  bca, Wf, bf);
  k_heads<<<(N + 15) / 16, 256, 0, stream>>>(A, Wf, bf, out, N);
  k_time<<<(N + 15) / 16, 256, 0, stream>>>(x0, Wtf, btf, out + (size_t)N * 50, N);
}

// Round 2
// 532.744 us; speedup vs baseline: 1.2905x; 1.2905x over previous
//
#include <hip/hip_runtime.h>
#include <math.h>

// ---------------------------------------------------------------------------
// GCN forward: 2 sparse aggregations (CSR, built on-device) + small dense GEMMs
// with fused head weights. All fp32.
// R1: k_heads/k_gemm128 restructured for occupancy (W from L2, only A in LDS);
//     dinv pre-scaling folded into row tables so agg inner loop is load+add.
// ---------------------------------------------------------------------------

static __device__ __forceinline__ float wave_max64(float v) {
#pragma unroll
  for (int o = 32; o; o >>= 1) v = fmaxf(v, __shfl_xor(v, o, 64));
  return v;
}
static __device__ __forceinline__ float wave_sum64(float v) {
#pragma unroll
  for (int o = 32; o; o >>= 1) v += __shfl_xor(v, o, 64);
  return v;
}

// ---- zero int buffer ------------------------------------------------------
__global__ void k_zero(int* __restrict__ p, int n) {
  int i = blockIdx.x * blockDim.x + threadIdx.x;
  if (i < n) p[i] = 0;
}

// ---- degree count (in-degree over dst) ------------------------------------
__global__ void k_deg(const int* __restrict__ dst, int E, int* __restrict__ deg) {
  int e = blockIdx.x * blockDim.x + threadIdx.x;
  if (e < E) atomicAdd(&deg[dst[e]], 1);
}

// ---- 3-kernel exclusive scan over N ints (grid <= 256 blocks of 256) ------
__global__ void k_scan1(const int* __restrict__ deg, int n,
                        int* __restrict__ excl, int* __restrict__ bsum) {
  __shared__ int sm[256];
  int i = blockIdx.x * 256 + threadIdx.x;
  int v = (i < n) ? deg[i] : 0;
  sm[threadIdx.x] = v;
  __syncthreads();
#pragma unroll
  for (int o = 1; o < 256; o <<= 1) {
    int t = (threadIdx.x >= o) ? sm[threadIdx.x - o] : 0;
    __syncthreads();
    sm[threadIdx.x] += t;
    __syncthreads();
  }
  if (i < n) excl[i] = sm[threadIdx.x] - v;
  if (threadIdx.x == 255) bsum[blockIdx.x] = sm[255];
}

__global__ void k_scan2(int* __restrict__ bsum, int nb) {
  __shared__ int sm[256];
  int v = (threadIdx.x < nb) ? bsum[threadIdx.x] : 0;
  sm[threadIdx.x] = v;
  __syncthreads();
#pragma unroll
  for (int o = 1; o < 256; o <<= 1) {
    int t = (threadIdx.x >= o) ? sm[threadIdx.x - o] : 0;
    __syncthreads();
    sm[threadIdx.x] += t;
    __syncthreads();
  }
  if (threadIdx.x < nb) bsum[threadIdx.x] = sm[threadIdx.x] - v;  // exclusive
}

__global__ void k_finalize(int* __restrict__ row_off, const int* __restrict__ bsum,
                           const int* __restrict__ deg, int* __restrict__ cursor,
                           float* __restrict__ dinv, int n) {
  int i = blockIdx.x * 256 + threadIdx.x;
  if (i < n) {
    int ro = row_off[i] + bsum[blockIdx.x];
    row_off[i] = ro;
    cursor[i] = ro;
    dinv[i] = rsqrtf((float)(deg[i] + 1));  // +1 self-loop
  }
}

// ---- CSR fill -------------------------------------------------------------
__global__ void k_fill(const int* __restrict__ src, const int* __restrict__ dst,
                       int E, int* __restrict__ cursor, int* __restrict__ csr) {
  int e = blockIdx.x * blockDim.x + threadIdx.x;
  if (e < E) {
    int d = dst[e];
    int p = atomicAdd(&cursor[d], 1);
    csr[p] = src[e];
  }
}

// ---- row pre-scale: Y[i][:] = dinv[i] * X[i][:]  (float4 per thread) ------
__global__ __launch_bounds__(256) void k_scale(
    const float* __restrict__ X, const float* __restrict__ dinv,
    float* __restrict__ Y, int n) {
  int t = blockIdx.x * 256 + threadIdx.x;
  int total = n * 32;  // float4s
  if (t < total) {
    int row = t >> 5;
    float d = dinv[row];
    float4 v = reinterpret_cast<const float4*>(X)[t];
    v.x *= d; v.y *= d; v.z *= d; v.w *= d;
    reinterpret_cast<float4*>(Y)[t] = v;
  }
}

// ---- aggregation on pre-scaled rows: out[i] = dinv[i]*( sum_s Y[s] + Y[i] )
// one wave per node; lane holds 2 consecutive floats of the 128-wide row.
__global__ __launch_bounds__(256) void k_agg(
    const float* __restrict__ Y, float* __restrict__ out,
    const int* __restrict__ row_off, const int* __restrict__ deg,
    const int* __restrict__ csr, const float* __restrict__ dinv, int n) {
  int wave = threadIdx.x >> 6;
  int lane = threadIdx.x & 63;
  int i = blockIdx.x * 4 + wave;
  if (i >= n) return;
  int start = row_off[i];
  int cnt = deg[i];
  const float2* Yf2 = reinterpret_cast<const float2*>(Y);
  float ax = 0.f, ay = 0.f;
  int j = 0;
  for (; j + 1 < cnt; j += 2) {
    int s0 = csr[start + j];
    int s1 = csr[start + j + 1];
    float2 v0 = Yf2[(size_t)s0 * 64 + lane];
    float2 v1 = Yf2[(size_t)s1 * 64 + lane];
    ax += v0.x + v1.x;
    ay += v0.y + v1.y;
  }
  if (j < cnt) {
    int s0 = csr[start + j];
    float2 v0 = Yf2[(size_t)s0 * 64 + lane];
    ax += v0.x;
    ay += v0.y;
  }
  float2 vs = Yf2[(size_t)i * 64 + lane];
  float di = dinv[i];
  float2 r;
  r.x = (ax + vs.x) * di;
  r.y = (ay + vs.y) * di;
  reinterpret_cast<float2*>(out)[(size_t)i * 64 + lane] = r;
}

// ---- dense 128x128 GEMM: out = dinv[r] * relu(A @ W + b) ------------------
// block 256 = 4 waves; 64 rows/block (16/wave). A in LDS (32KB); W from L2.
// lane: cg=lane&31 -> cols 4cg..4cg+3 ; rh=lane>>5 -> rows rl0+rh*8+ri.
__global__ __launch_bounds__(256) void k_gemm128(
    const float* __restrict__ A, const float* __restrict__ W,
    const float* __restrict__ bias, const float* __restrict__ dinv,
    float* __restrict__ out, int n) {
  __shared__ float sA[64][128];
  int rowBase = blockIdx.x * 64;
  for (int t = threadIdx.x; t < 64 * 32; t += 256) {
    int r = t >> 5, c4 = t & 31;
    int gr = rowBase + r;
    float4 v = (gr < n) ? reinterpret_cast<const float4*>(A)[(size_t)gr * 32 + c4]
                        : make_float4(0.f, 0.f, 0.f, 0.f);
    reinterpret_cast<float4*>(&sA[0][0])[t] = v;
  }
  __syncthreads();
  int wave = threadIdx.x >> 6, lane = threadIdx.x & 63;
  int cg = lane & 31, rh = lane >> 5;
  int rl0 = wave * 16 + rh * 8;
  const float4* Wf4 = reinterpret_cast<const float4*>(W);
  const float4* sAf4 = reinterpret_cast<const float4*>(&sA[0][0]);
  float acc[8][4] = {};  // [ri][q]
  for (int k4 = 0; k4 < 32; ++k4) {
    float4 w0 = Wf4[(k4 * 4 + 0) * 32 + cg];
    float4 w1 = Wf4[(k4 * 4 + 1) * 32 + cg];
    float4 w2 = Wf4[(k4 * 4 + 2) * 32 + cg];
    float4 w3 = Wf4[(k4 * 4 + 3) * 32 + cg];
#pragma unroll
    for (int ri = 0; ri < 8; ++ri) {
      float4 a = sAf4[(rl0 + ri) * 32 + k4];
      acc[ri][0] += a.x * w0.x + a.y * w1.x + a.z * w2.x + a.w * w3.x;
      acc[ri][1] += a.x * w0.y + a.y * w1.y + a.z * w2.y + a.w * w3.y;
      acc[ri][2] += a.x * w0.z + a.y * w1.z + a.z * w2.z + a.w * w3.z;
      acc[ri][3] += a.x * w0.w + a.y * w1.w + a.z * w2.w + a.w * w3.w;
    }
  }
  float4 b4 = reinterpret_cast<const float4*>(bias)[cg];
#pragma unroll
  for (int ri = 0; ri < 8; ++ri) {
    int r = rowBase + rl0 + ri;
    if (r < n) {
      float d = dinv[r];
      float4 o;
      o.x = fmaxf(acc[ri][0] + b4.x, 0.f) * d;
      o.y = fmaxf(acc[ri][1] + b4.y, 0.f) * d;
      o.z = fmaxf(acc[ri][2] + b4.z, 0.f) * d;
      o.w = fmaxf(acc[ri][3] + b4.w, 0.f) * d;
      reinterpret_cast<float4*>(out)[(size_t)r * 32 + cg] = o;
    }
  }
}

// ---- fuse head weights: Wf[128][256] cols: [0,20)=Wt@Wct, [20,50)=Ws@Wcs,
// [50,250)=Wa@Wca, [250,256)=0. bf likewise (b1st@W2nd + b2nd). -------------
__global__ void k_fuse(const float* __restrict__ Wt, const float* __restrict__ bt,
                       const float* __restrict__ Wct, const float* __restrict__ bct,
                       const float* __restrict__ Ws, const float* __restrict__ bs,
                       const float* __restrict__ Wcs, const float* __restrict__ bcs,
                       const float* __restrict__ Wa, const float* __restrict__ ba,
                       const float* __restrict__ Wca, const float* __restrict__ bca,
                       float* __restrict__ Wf, float* __restrict__ bf) {
  int c = blockIdx.x;   // 0..255
  int i = threadIdx.x;  // 0..127
  float acc = 0.f, bacc = 0.f;
  if (c < 20) {
    for (int k = 0; k < 20; ++k) {
      float w2 = Wct[k * 20 + c];
      acc += Wt[i * 20 + k] * w2;
      bacc += bt[k] * w2;
    }
    bacc += bct[c];
  } else if (c < 50) {
    int cc = c - 20;
    for (int k = 0; k < 30; ++k) {
      float w2 = Wcs[k * 30 + cc];
      acc += Ws[i * 30 + k] * w2;
      bacc += bs[k] * w2;
    }
    bacc += bcs[cc];
  } else if (c < 250) {
    int cc = c - 50;
    for (int k = 0; k < 200; ++k) {
      float w2 = Wca[k * 200 + cc];
      acc += Wa[i * 200 + k] * w2;
      bacc += ba[k] * w2;
    }
    bacc += bca[cc];
  }
  Wf[i * 256 + c] = acc;
  if (i == 0) bf[c] = bacc;
}

// ---- heads: z = AH @ Wf + bf ; per-segment softmax ; scatter to out -------
// block 256 = 4 waves; 64 rows/block (16/wave). A in LDS; Wf from L2.
// lane covers cols 4l..4l+3 of 256.
__global__ __launch_bounds__(256) void k_heads(
    const float* __restrict__ AH, const float* __restrict__ Wf,
    const float* __restrict__ bf, float* __restrict__ out, int n) {
  __shared__ float sA[64][128];
  int rowBase = blockIdx.x * 64;
  for (int t = threadIdx.x; t < 64 * 32; t += 256) {
    int r = t >> 5, c4 = t & 31;
    int gr = rowBase + r;
    float4 v = (gr < n) ? reinterpret_cast<const float4*>(AH)[(size_t)gr * 32 + c4]
                        : make_float4(0.f, 0.f, 0.f, 0.f);
    reinterpret_cast<float4*>(&sA[0][0])[t] = v;
  }
  __syncthreads();
  int wave = threadIdx.x >> 6, lane = threadIdx.x & 63;
  int rl0 = wave * 16;
  const float4* Wff4 = reinterpret_cast<const float4*>(Wf);
  const float4* sAf4 = reinterpret_cast<const float4*>(&sA[0][0]);
  float acc[16][4] = {};  // [ri][q]
  for (int k4 = 0; k4 < 32; ++k4) {
    float4 w0 = Wff4[(k4 * 4 + 0) * 64 + lane];
    float4 w1 = Wff4[(k4 * 4 + 1) * 64 + lane];
    float4 w2 = Wff4[(k4 * 4 + 2) * 64 + lane];
    float4 w3 = Wff4[(k4 * 4 + 3) * 64 + lane];
#pragma unroll
    for (int ri = 0; ri < 16; ++ri) {
      float4 a = sAf4[(rl0 + ri) * 32 + k4];
      acc[ri][0] += a.x * w0.x + a.y * w1.x + a.z * w2.x + a.w * w3.x;
      acc[ri][1] += a.x * w0.y + a.y * w1.y + a.z * w2.y + a.w * w3.y;
      acc[ri][2] += a.x * w0.z + a.y * w1.z + a.z * w2.z + a.w * w3.z;
      acc[ri][3] += a.x * w0.w + a.y * w1.w + a.z * w2.w + a.w * w3.w;
    }
  }
  float4 b4 = reinterpret_cast<const float4*>(bf)[lane];
  float bq[4] = {b4.x, b4.y, b4.z, b4.w};
  float* outT = out;
  float* outS = out + (size_t)n * 20;
  float* outA = out + (size_t)n * 65;
  int c0 = lane * 4;
#pragma unroll
  for (int ri = 0; ri < 16; ++ri) {
    int r = rowBase + rl0 + ri;
    if (r >= n) continue;  // wave-uniform
    float v[4];
#pragma unroll
    for (int q = 0; q < 4; ++q) v[q] = acc[ri][q] + bq[q];
    float e[4];
    // ---- type head: cols [0,20)
    {
      float m = -INFINITY;
#pragma unroll
      for (int q = 0; q < 4; ++q) { int c = c0 + q; if (c < 20) m = fmaxf(m, v[q]); }
      m = wave_max64(m);
      float s = 0.f;
#pragma unroll
      for (int q = 0; q < 4; ++q) {
        int c = c0 + q;
        e[q] = (c < 20) ? expf(v[q] - m) : 0.f;
        s += e[q];
      }
      s = wave_sum64(s);
      float inv = 1.f / s;
#pragma unroll
      for (int q = 0; q < 4; ++q) { int c = c0 + q; if (c < 20) outT[(size_t)r * 20 + c] = e[q] * inv; }
    }
    // ---- school head: cols [20,50)
    {
      float m = -INFINITY;
#pragma unroll
      for (int q = 0; q < 4; ++q) { int c = c0 + q; if (c >= 20 && c < 50) m = fmaxf(m, v[q]); }
      m = wave_max64(m);
      float s = 0.f;
#pragma unroll
      for (int q = 0; q < 4; ++q) {
        int c = c0 + q;
        e[q] = (c >= 20 && c < 50) ? expf(v[q] - m) : 0.f;
        s += e[q];
      }
      s = wave_sum64(s);
      float inv = 1.f / s;
#pragma unroll
      for (int q = 0; q < 4; ++q) { int c = c0 + q; if (c >= 20 && c < 50) outS[(size_t)r * 30 + (c - 20)] = e[q] * inv; }
    }
    // ---- author head: cols [50,250)
    {
      float m = -INFINITY;
#pragma unroll
      for (int q = 0; q < 4; ++q) { int c = c0 + q; if (c >= 50 && c < 250) m = fmaxf(m, v[q]); }
      m = wave_max64(m);
      float s = 0.f;
#pragma unroll
      for (int q = 0; q < 4; ++q) {
        int c = c0 + q;
        e[q] = (c >= 50 && c < 250) ? expf(v[q] - m) : 0.f;
        s += e[q];
      }
      s = wave_sum64(s);
      float inv = 1.f / s;
#pragma unroll
      for (int q = 0; q < 4; ++q) { int c = c0 + q; if (c >= 50 && c < 250) outA[(size_t)r * 200 + (c - 50)] = e[q] * inv; }
    }
  }
}

// ---- time head: softmax(x0 @ Wtf + btf) -----------------------------------
// block 256 = 16 rows x 16 lanes (col j, j<15 active).
__global__ __launch_bounds__(256) void k_time(
    const float* __restrict__ x0, const float* __restrict__ Wtf,
    const float* __restrict__ btf, float* __restrict__ outT, int n) {
  __shared__ float sW[128][16];
  __shared__ float sb[16];
  for (int t = threadIdx.x; t < 128 * 16; t += 256) {
    int k = t >> 4, j = t & 15;
    sW[k][j] = (j < 15) ? Wtf[k * 15 + j] : 0.f;
  }
  if (threadIdx.x < 16) sb[threadIdx.x] = (threadIdx.x < 15) ? btf[threadIdx.x] : 0.f;
  __syncthreads();
  int j = threadIdx.x & 15;
  int rl = threadIdx.x >> 4;
  int r = blockIdx.x * 16 + rl;
  if (r >= n) return;
  float acc = sb[j];
  const float4* xr = reinterpret_cast<const float4*>(x0 + (size_t)r * 128);
  for (int k4 = 0; k4 < 32; ++k4) {
    float4 xv = xr[k4];
    acc += xv.x * sW[k4 * 4 + 0][j] + xv.y * sW[k4 * 4 + 1][j] +
           xv.z * sW[k4 * 4 + 2][j] + xv.w * sW[k4 * 4 + 3][j];
  }
  float m = (j < 15) ? acc : -INFINITY;
#pragma unroll
  for (int o = 8; o; o >>= 1) m = fmaxf(m, __shfl_xor(m, o, 16));
  float e = (j < 15) ? expf(acc - m) : 0.f;
  float s = e;
#pragma unroll
  for (int o = 8; o; o >>= 1) s += __shfl_xor(s, o, 16);
  if (j < 15) outT[(size_t)r * 15 + j] = e / s;
}

// ---------------------------------------------------------------------------
extern "C" void kernel_launch(void* const* d_in, const int* in_sizes, int n_in,
                              void* d_out, int out_size, void* d_ws, size_t ws_size,
                              hipStream_t stream) {
  const float* x0 = (const float*)d_in[0];
  const int* ei = (const int*)d_in[1];
  const float* W1 = (const float*)d_in[2];
  const float* b1 = (const float*)d_in[3];
  const float* Wt = (const float*)d_in[4];
  const float* bt = (const float*)d_in[5];
  const float* Ws = (const float*)d_in[6];
  const float* bs = (const float*)d_in[7];
  const float* Wa = (const float*)d_in[8];
  const float* ba = (const float*)d_in[9];
  const float* Wct = (const float*)d_in[10];
  const float* bct = (const float*)d_in[11];
  const float* Wcs = (const float*)d_in[12];
  const float* bcs = (const float*)d_in[13];
  const float* Wtf = (const float*)d_in[14];
  const float* btf = (const float*)d_in[15];
  const float* Wca = (const float*)d_in[16];
  const float* bca = (const float*)d_in[17];
  (void)n_in; (void)out_size; (void)ws_size;

  int N = in_sizes[0] / 128;
  int E = in_sizes[1] / 2;
  float* out = (float*)d_out;

  char* ws = (char*)d_ws;
  size_t off = 0;
  auto alloc = [&](size_t bytes) -> void* {
    void* p = ws + off;
    off = (off + bytes + 255) & ~(size_t)255;
    return p;
  };
  int* deg = (int*)alloc((size_t)N * 4);
  int* row_off = (int*)alloc((size_t)N * 4);
  int* bsum = (int*)alloc(256 * 4);
  int* cursor = (int*)alloc((size_t)N * 4);
  float* dinv = (float*)alloc((size_t)N * 4);
  int* csr = (int*)alloc((size_t)E * 4);
  float* Wf = (float*)alloc((size_t)128 * 256 * 4);
  float* bf = (float*)alloc(256 * 4);
  float* A = (float*)alloc((size_t)N * 128 * 4);
  float* B = (float*)alloc((size_t)N * 128 * 4);

  const int* srcp = ei;
  const int* dstp = ei + E;
  int gE = (E + 255) / 256;
  int gN = (N + 255) / 256;  // 196 <= 256, required by k_scan2

  k_zero<<<gN, 256, 0, stream>>>(deg, N);
  k_deg<<<gE, 256, 0, stream>>>(dstp, E, deg);
  k_scan1<<<gN, 256, 0, stream>>>(deg, N, row_off, bsum);
  k_scan2<<<1, 256, 0, stream>>>(bsum, gN);
  k_finalize<<<gN, 256, 0, stream>>>(row_off, bsum, deg, cursor, dinv, N);
  k_fill<<<gE, 256, 0, stream>>>(srcp, dstp, E, cursor, csr);
  // Y0 = dinv*x0 -> B ; A = agg(Y0)
  k_scale<<<(N * 32 + 255) / 256, 256, 0, stream>>>(x0, dinv, B, N);
  k_agg<<<(N + 3) / 4, 256, 0, stream>>>(B, A, row_off, deg, csr, dinv, N);
  // B = dinv*relu(A@W1+b1)
  k_gemm128<<<(N + 63) / 64, 256, 0, stream>>>(A, W1, b1, dinv, B, N);
  // A = agg(B)  (already pre-scaled)
  k_agg<<<(N + 3) / 4, 256, 0, stream>>>(B, A, row_off, deg, csr, dinv, N);
  k_fuse<<<256, 128, 0, stream>>>(Wt, bt, Wct, bct, Ws, bs, Wcs, bcs, Wa, ba, Wca,
                                  bca, Wf, bf);
  k_heads<<<(N + 63) / 64, 256, 0, stream>>>(A, Wf, bf, out, N);
  k_time<<<(N + 15) / 16, 256, 0, stream>>>(x0, Wtf, btf, out + (size_t)N * 50, N);
}

// Round 3
// 480.621 us; speedup vs baseline: 1.4305x; 1.1084x over previous
//
#include <hip/hip_runtime.h>
#include <math.h>

// ---------------------------------------------------------------------------
// GCN forward: 2 sparse aggregations (CSR, built on-device) + small dense GEMMs
// with fused head weights. All fp32.
// R2: k_heads split into pure GEMM (logits out) + wave-per-row softmax kernel
//     (cross-lane chains now TLP-hidden). k_agg unrolled x4.
// ---------------------------------------------------------------------------

static __device__ __forceinline__ float wave_max64(float v) {
#pragma unroll
  for (int o = 32; o; o >>= 1) v = fmaxf(v, __shfl_xor(v, o, 64));
  return v;
}
static __device__ __forceinline__ float wave_sum64(float v) {
#pragma unroll
  for (int o = 32; o; o >>= 1) v += __shfl_xor(v, o, 64);
  return v;
}

// ---- zero int buffer ------------------------------------------------------
__global__ void k_zero(int* __restrict__ p, int n) {
  int i = blockIdx.x * blockDim.x + threadIdx.x;
  if (i < n) p[i] = 0;
}

// ---- degree count (in-degree over dst) ------------------------------------
__global__ void k_deg(const int* __restrict__ dst, int E, int* __restrict__ deg) {
  int e = blockIdx.x * blockDim.x + threadIdx.x;
  if (e < E) atomicAdd(&deg[dst[e]], 1);
}

// ---- 3-kernel exclusive scan over N ints (grid <= 256 blocks of 256) ------
__global__ void k_scan1(const int* __restrict__ deg, int n,
                        int* __restrict__ excl, int* __restrict__ bsum) {
  __shared__ int sm[256];
  int i = blockIdx.x * 256 + threadIdx.x;
  int v = (i < n) ? deg[i] : 0;
  sm[threadIdx.x] = v;
  __syncthreads();
#pragma unroll
  for (int o = 1; o < 256; o <<= 1) {
    int t = (threadIdx.x >= o) ? sm[threadIdx.x - o] : 0;
    __syncthreads();
    sm[threadIdx.x] += t;
    __syncthreads();
  }
  if (i < n) excl[i] = sm[threadIdx.x] - v;
  if (threadIdx.x == 255) bsum[blockIdx.x] = sm[255];
}

__global__ void k_scan2(int* __restrict__ bsum, int nb) {
  __shared__ int sm[256];
  int v = (threadIdx.x < nb) ? bsum[threadIdx.x] : 0;
  sm[threadIdx.x] = v;
  __syncthreads();
#pragma unroll
  for (int o = 1; o < 256; o <<= 1) {
    int t = (threadIdx.x >= o) ? sm[threadIdx.x - o] : 0;
    __syncthreads();
    sm[threadIdx.x] += t;
    __syncthreads();
  }
  if (threadIdx.x < nb) bsum[threadIdx.x] = sm[threadIdx.x] - v;  // exclusive
}

__global__ void k_finalize(int* __restrict__ row_off, const int* __restrict__ bsum,
                           const int* __restrict__ deg, int* __restrict__ cursor,
                           float* __restrict__ dinv, int n) {
  int i = blockIdx.x * 256 + threadIdx.x;
  if (i < n) {
    int ro = row_off[i] + bsum[blockIdx.x];
    row_off[i] = ro;
    cursor[i] = ro;
    dinv[i] = rsqrtf((float)(deg[i] + 1));  // +1 self-loop
  }
}

// ---- CSR fill -------------------------------------------------------------
__global__ void k_fill(const int* __restrict__ src, const int* __restrict__ dst,
                       int E, int* __restrict__ cursor, int* __restrict__ csr) {
  int e = blockIdx.x * blockDim.x + threadIdx.x;
  if (e < E) {
    int d = dst[e];
    int p = atomicAdd(&cursor[d], 1);
    csr[p] = src[e];
  }
}

// ---- row pre-scale: Y[i][:] = dinv[i] * X[i][:]  (float4 per thread) ------
__global__ __launch_bounds__(256) void k_scale(
    const float* __restrict__ X, const float* __restrict__ dinv,
    float* __restrict__ Y, int n) {
  int t = blockIdx.x * 256 + threadIdx.x;
  int total = n * 32;  // float4s
  if (t < total) {
    int row = t >> 5;
    float d = dinv[row];
    float4 v = reinterpret_cast<const float4*>(X)[t];
    v.x *= d; v.y *= d; v.z *= d; v.w *= d;
    reinterpret_cast<float4*>(Y)[t] = v;
  }
}

// ---- aggregation on pre-scaled rows: out[i] = dinv[i]*( sum_s Y[s] + Y[i] )
// one wave per node; lane holds 2 consecutive floats of the 128-wide row.
__global__ __launch_bounds__(256) void k_agg(
    const float* __restrict__ Y, float* __restrict__ out,
    const int* __restrict__ row_off, const int* __restrict__ deg,
    const int* __restrict__ csr, const float* __restrict__ dinv, int n) {
  int wave = threadIdx.x >> 6;
  int lane = threadIdx.x & 63;
  int i = blockIdx.x * 4 + wave;
  if (i >= n) return;
  int start = row_off[i];
  int cnt = deg[i];
  const float2* Yf2 = reinterpret_cast<const float2*>(Y);
  float ax = 0.f, ay = 0.f;
  int j = 0;
  for (; j + 3 < cnt; j += 4) {
    int s0 = csr[start + j];
    int s1 = csr[start + j + 1];
    int s2 = csr[start + j + 2];
    int s3 = csr[start + j + 3];
    float2 v0 = Yf2[(size_t)s0 * 64 + lane];
    float2 v1 = Yf2[(size_t)s1 * 64 + lane];
    float2 v2 = Yf2[(size_t)s2 * 64 + lane];
    float2 v3 = Yf2[(size_t)s3 * 64 + lane];
    ax += (v0.x + v1.x) + (v2.x + v3.x);
    ay += (v0.y + v1.y) + (v2.y + v3.y);
  }
  for (; j < cnt; ++j) {
    int s0 = csr[start + j];
    float2 v0 = Yf2[(size_t)s0 * 64 + lane];
    ax += v0.x;
    ay += v0.y;
  }
  float2 vs = Yf2[(size_t)i * 64 + lane];
  float di = dinv[i];
  float2 r;
  r.x = (ax + vs.x) * di;
  r.y = (ay + vs.y) * di;
  reinterpret_cast<float2*>(out)[(size_t)i * 64 + lane] = r;
}

// ---- dense 128x128 GEMM: out = dinv[r] * relu(A @ W + b) ------------------
// block 256 = 4 waves; 64 rows/block (16/wave). A in LDS (32KB); W from L2.
__global__ __launch_bounds__(256) void k_gemm128(
    const float* __restrict__ A, const float* __restrict__ W,
    const float* __restrict__ bias, const float* __restrict__ dinv,
    float* __restrict__ out, int n) {
  __shared__ float sA[64][128];
  int rowBase = blockIdx.x * 64;
  for (int t = threadIdx.x; t < 64 * 32; t += 256) {
    int r = t >> 5, c4 = t & 31;
    int gr = rowBase + r;
    float4 v = (gr < n) ? reinterpret_cast<const float4*>(A)[(size_t)gr * 32 + c4]
                        : make_float4(0.f, 0.f, 0.f, 0.f);
    reinterpret_cast<float4*>(&sA[0][0])[t] = v;
  }
  __syncthreads();
  int wave = threadIdx.x >> 6, lane = threadIdx.x & 63;
  int cg = lane & 31, rh = lane >> 5;
  int rl0 = wave * 16 + rh * 8;
  const float4* Wf4 = reinterpret_cast<const float4*>(W);
  const float4* sAf4 = reinterpret_cast<const float4*>(&sA[0][0]);
  float acc[8][4] = {};  // [ri][q]
  for (int k4 = 0; k4 < 32; ++k4) {
    float4 w0 = Wf4[(k4 * 4 + 0) * 32 + cg];
    float4 w1 = Wf4[(k4 * 4 + 1) * 32 + cg];
    float4 w2 = Wf4[(k4 * 4 + 2) * 32 + cg];
    float4 w3 = Wf4[(k4 * 4 + 3) * 32 + cg];
#pragma unroll
    for (int ri = 0; ri < 8; ++ri) {
      float4 a = sAf4[(rl0 + ri) * 32 + k4];
      acc[ri][0] += a.x * w0.x + a.y * w1.x + a.z * w2.x + a.w * w3.x;
      acc[ri][1] += a.x * w0.y + a.y * w1.y + a.z * w2.y + a.w * w3.y;
      acc[ri][2] += a.x * w0.z + a.y * w1.z + a.z * w2.z + a.w * w3.z;
      acc[ri][3] += a.x * w0.w + a.y * w1.w + a.z * w2.w + a.w * w3.w;
    }
  }
  float4 b4 = reinterpret_cast<const float4*>(bias)[cg];
#pragma unroll
  for (int ri = 0; ri < 8; ++ri) {
    int r = rowBase + rl0 + ri;
    if (r < n) {
      float d = dinv[r];
      float4 o;
      o.x = fmaxf(acc[ri][0] + b4.x, 0.f) * d;
      o.y = fmaxf(acc[ri][1] + b4.y, 0.f) * d;
      o.z = fmaxf(acc[ri][2] + b4.z, 0.f) * d;
      o.w = fmaxf(acc[ri][3] + b4.w, 0.f) * d;
      reinterpret_cast<float4*>(out)[(size_t)r * 32 + cg] = o;
    }
  }
}

// ---- fuse head weights: Wf[128][256] cols: [0,20)=Wt@Wct, [20,50)=Ws@Wcs,
// [50,250)=Wa@Wca, [250,256)=0. bf likewise (b1st@W2nd + b2nd). -------------
__global__ void k_fuse(const float* __restrict__ Wt, const float* __restrict__ bt,
                       const float* __restrict__ Wct, const float* __restrict__ bct,
                       const float* __restrict__ Ws, const float* __restrict__ bs,
                       const float* __restrict__ Wcs, const float* __restrict__ bcs,
                       const float* __restrict__ Wa, const float* __restrict__ ba,
                       const float* __restrict__ Wca, const float* __restrict__ bca,
                       float* __restrict__ Wf, float* __restrict__ bf) {
  int c = blockIdx.x;   // 0..255
  int i = threadIdx.x;  // 0..127
  float acc = 0.f, bacc = 0.f;
  if (c < 20) {
    for (int k = 0; k < 20; ++k) {
      float w2 = Wct[k * 20 + c];
      acc += Wt[i * 20 + k] * w2;
      bacc += bt[k] * w2;
    }
    bacc += bct[c];
  } else if (c < 50) {
    int cc = c - 20;
    for (int k = 0; k < 30; ++k) {
      float w2 = Wcs[k * 30 + cc];
      acc += Ws[i * 30 + k] * w2;
      bacc += bs[k] * w2;
    }
    bacc += bcs[cc];
  } else if (c < 250) {
    int cc = c - 50;
    for (int k = 0; k < 200; ++k) {
      float w2 = Wca[k * 200 + cc];
      acc += Wa[i * 200 + k] * w2;
      bacc += ba[k] * w2;
    }
    bacc += bca[cc];
  }
  Wf[i * 256 + c] = acc;
  if (i == 0) bf[c] = bacc;
}

// ---- heads GEMM: L = AH @ Wf + bf  (logits, [n][256] coalesced) -----------
// block 256 = 4 waves; 64 rows/block (16/wave). A in LDS; Wf from L2.
__global__ __launch_bounds__(256) void k_heads_gemm(
    const float* __restrict__ AH, const float* __restrict__ Wf,
    const float* __restrict__ bf, float* __restrict__ L, int n) {
  __shared__ float sA[64][128];
  int rowBase = blockIdx.x * 64;
  for (int t = threadIdx.x; t < 64 * 32; t += 256) {
    int r = t >> 5, c4 = t & 31;
    int gr = rowBase + r;
    float4 v = (gr < n) ? reinterpret_cast<const float4*>(AH)[(size_t)gr * 32 + c4]
                        : make_float4(0.f, 0.f, 0.f, 0.f);
    reinterpret_cast<float4*>(&sA[0][0])[t] = v;
  }
  __syncthreads();
  int wave = threadIdx.x >> 6, lane = threadIdx.x & 63;
  int rl0 = wave * 16;
  const float4* Wff4 = reinterpret_cast<const float4*>(Wf);
  const float4* sAf4 = reinterpret_cast<const float4*>(&sA[0][0]);
  float acc[16][4] = {};  // [ri][q]
  for (int k4 = 0; k4 < 32; ++k4) {
    float4 w0 = Wff4[(k4 * 4 + 0) * 64 + lane];
    float4 w1 = Wff4[(k4 * 4 + 1) * 64 + lane];
    float4 w2 = Wff4[(k4 * 4 + 2) * 64 + lane];
    float4 w3 = Wff4[(k4 * 4 + 3) * 64 + lane];
#pragma unroll
    for (int ri = 0; ri < 16; ++ri) {
      float4 a = sAf4[(rl0 + ri) * 32 + k4];
      acc[ri][0] += a.x * w0.x + a.y * w1.x + a.z * w2.x + a.w * w3.x;
      acc[ri][1] += a.x * w0.y + a.y * w1.y + a.z * w2.y + a.w * w3.y;
      acc[ri][2] += a.x * w0.z + a.y * w1.z + a.z * w2.z + a.w * w3.z;
      acc[ri][3] += a.x * w0.w + a.y * w1.w + a.z * w2.w + a.w * w3.w;
    }
  }
  float4 b4 = reinterpret_cast<const float4*>(bf)[lane];
#pragma unroll
  for (int ri = 0; ri < 16; ++ri) {
    int r = rowBase + rl0 + ri;
    if (r < n) {
      float4 o;
      o.x = acc[ri][0] + b4.x;
      o.y = acc[ri][1] + b4.y;
      o.z = acc[ri][2] + b4.z;
      o.w = acc[ri][3] + b4.w;
      reinterpret_cast<float4*>(L)[(size_t)r * 64 + lane] = o;
    }
  }
}

// ---- segmented softmax over logits: one WAVE per row ----------------------
// lane holds cols 4l..4l+3. type [0,20) school [20,50) author [50,250).
__global__ __launch_bounds__(256) void k_softmax3(
    const float* __restrict__ L, float* __restrict__ out, int n) {
  int wave = threadIdx.x >> 6, lane = threadIdx.x & 63;
  int r = blockIdx.x * 4 + wave;
  if (r >= n) return;
  float4 v4 = reinterpret_cast<const float4*>(L)[(size_t)r * 64 + lane];
  float v[4] = {v4.x, v4.y, v4.z, v4.w};
  int c0 = lane * 4;
  float mT = -INFINITY, mS = -INFINITY, mA = -INFINITY;
#pragma unroll
  for (int q = 0; q < 4; ++q) {
    int c = c0 + q;
    if (c < 20) mT = fmaxf(mT, v[q]);
    else if (c < 50) mS = fmaxf(mS, v[q]);
    else if (c < 250) mA = fmaxf(mA, v[q]);
  }
#pragma unroll
  for (int o = 32; o; o >>= 1) {
    mT = fmaxf(mT, __shfl_xor(mT, o, 64));
    mS = fmaxf(mS, __shfl_xor(mS, o, 64));
    mA = fmaxf(mA, __shfl_xor(mA, o, 64));
  }
  float e[4];
  float sT = 0.f, sS = 0.f, sA = 0.f;
#pragma unroll
  for (int q = 0; q < 4; ++q) {
    int c = c0 + q;
    float m = (c < 20) ? mT : (c < 50) ? mS : mA;
    float ex = __expf(v[q] - m);
    e[q] = ex;
    if (c < 20) sT += ex;
    else if (c < 50) sS += ex;
    else if (c < 250) sA += ex;
  }
#pragma unroll
  for (int o = 32; o; o >>= 1) {
    sT += __shfl_xor(sT, o, 64);
    sS += __shfl_xor(sS, o, 64);
    sA += __shfl_xor(sA, o, 64);
  }
  float iT = 1.f / sT, iS = 1.f / sS, iA = 1.f / sA;
  float* outT = out;
  float* outS = out + (size_t)n * 20;
  float* outA = out + (size_t)n * 65;
#pragma unroll
  for (int q = 0; q < 4; ++q) {
    int c = c0 + q;
    if (c < 20) outT[(size_t)r * 20 + c] = e[q] * iT;
    else if (c < 50) outS[(size_t)r * 30 + (c - 20)] = e[q] * iS;
    else if (c < 250) outA[(size_t)r * 200 + (c - 50)] = e[q] * iA;
  }
}

// ---- time head: softmax(x0 @ Wtf + btf) -----------------------------------
__global__ __launch_bounds__(256) void k_time(
    const float* __restrict__ x0, const float* __restrict__ Wtf,
    const float* __restrict__ btf, float* __restrict__ outT, int n) {
  __shared__ float sW[128][16];
  __shared__ float sb[16];
  for (int t = threadIdx.x; t < 128 * 16; t += 256) {
    int k = t >> 4, j = t & 15;
    sW[k][j] = (j < 15) ? Wtf[k * 15 + j] : 0.f;
  }
  if (threadIdx.x < 16) sb[threadIdx.x] = (threadIdx.x < 15) ? btf[threadIdx.x] : 0.f;
  __syncthreads();
  int j = threadIdx.x & 15;
  int rl = threadIdx.x >> 4;
  int r = blockIdx.x * 16 + rl;
  if (r >= n) return;
  float acc = sb[j];
  const float4* xr = reinterpret_cast<const float4*>(x0 + (size_t)r * 128);
  for (int k4 = 0; k4 < 32; ++k4) {
    float4 xv = xr[k4];
    acc += xv.x * sW[k4 * 4 + 0][j] + xv.y * sW[k4 * 4 + 1][j] +
           xv.z * sW[k4 * 4 + 2][j] + xv.w * sW[k4 * 4 + 3][j];
  }
  float m = (j < 15) ? acc : -INFINITY;
#pragma unroll
  for (int o = 8; o; o >>= 1) m = fmaxf(m, __shfl_xor(m, o, 16));
  float e = (j < 15) ? __expf(acc - m) : 0.f;
  float s = e;
#pragma unroll
  for (int o = 8; o; o >>= 1) s += __shfl_xor(s, o, 16);
  if (j < 15) outT[(size_t)r * 15 + j] = e / s;
}

// ---------------------------------------------------------------------------
extern "C" void kernel_launch(void* const* d_in, const int* in_sizes, int n_in,
                              void* d_out, int out_size, void* d_ws, size_t ws_size,
                              hipStream_t stream) {
  const float* x0 = (const float*)d_in[0];
  const int* ei = (const int*)d_in[1];
  const float* W1 = (const float*)d_in[2];
  const float* b1 = (const float*)d_in[3];
  const float* Wt = (const float*)d_in[4];
  const float* bt = (const float*)d_in[5];
  const float* Ws = (const float*)d_in[6];
  const float* bs = (const float*)d_in[7];
  const float* Wa = (const float*)d_in[8];
  const float* ba = (const float*)d_in[9];
  const float* Wct = (const float*)d_in[10];
  const float* bct = (const float*)d_in[11];
  const float* Wcs = (const float*)d_in[12];
  const float* bcs = (const float*)d_in[13];
  const float* Wtf = (const float*)d_in[14];
  const float* btf = (const float*)d_in[15];
  const float* Wca = (const float*)d_in[16];
  const float* bca = (const float*)d_in[17];
  (void)n_in; (void)out_size; (void)ws_size;

  int N = in_sizes[0] / 128;
  int E = in_sizes[1] / 2;
  float* out = (float*)d_out;

  char* ws = (char*)d_ws;
  size_t off = 0;
  auto alloc = [&](size_t bytes) -> void* {
    void* p = ws + off;
    off = (off + bytes + 255) & ~(size_t)255;
    return p;
  };
  int* deg = (int*)alloc((size_t)N * 4);
  int* row_off = (int*)alloc((size_t)N * 4);
  int* bsum = (int*)alloc(256 * 4);
  int* cursor = (int*)alloc((size_t)N * 4);
  float* dinv = (float*)alloc((size_t)N * 4);
  int* csr = (int*)alloc((size_t)E * 4);
  float* Wf = (float*)alloc((size_t)128 * 256 * 4);
  float* bf = (float*)alloc(256 * 4);
  float* A = (float*)alloc((size_t)N * 128 * 4);
  float* B = (float*)alloc((size_t)N * 256 * 4);  // doubles as logits buffer

  const int* srcp = ei;
  const int* dstp = ei + E;
  int gE = (E + 255) / 256;
  int gN = (N + 255) / 256;  // 196 <= 256, required by k_scan2

  k_zero<<<gN, 256, 0, stream>>>(deg, N);
  k_deg<<<gE, 256, 0, stream>>>(dstp, E, deg);
  k_scan1<<<gN, 256, 0, stream>>>(deg, N, row_off, bsum);
  k_scan2<<<1, 256, 0, stream>>>(bsum, gN);
  k_finalize<<<gN, 256, 0, stream>>>(row_off, bsum, deg, cursor, dinv, N);
  k_fill<<<gE, 256, 0, stream>>>(srcp, dstp, E, cursor, csr);
  // Y0 = dinv*x0 -> B ; A = agg(Y0)
  k_scale<<<(N * 32 + 255) / 256, 256, 0, stream>>>(x0, dinv, B, N);
  k_agg<<<(N + 3) / 4, 256, 0, stream>>>(B, A, row_off, deg, csr, dinv, N);
  // B = dinv*relu(A@W1+b1)
  k_gemm128<<<(N + 63) / 64, 256, 0, stream>>>(A, W1, b1, dinv, B, N);
  // A = agg(B)
  k_agg<<<(N + 3) / 4, 256, 0, stream>>>(B, A, row_off, deg, csr, dinv, N);
  k_fuse<<<256, 128, 0, stream>>>(Wt, bt, Wct, bct, Ws, bs, Wcs, bcs, Wa, ba, Wca,
                                  bca, Wf, bf);
  // L = A @ Wf + bf  (B reused as logits) ; then segmented softmax
  k_heads_gemm<<<(N + 63) / 64, 256, 0, stream>>>(A, Wf, bf, B, N);
  k_softmax3<<<(N + 3) / 4, 256, 0, stream>>>(B, out, N);
  k_time<<<(N + 15) / 16, 256, 0, stream>>>(x0, Wtf, btf, out + (size_t)N * 50, N);
}

// Round 4
// 433.863 us; speedup vs baseline: 1.5847x; 1.1078x over previous
//
#include <hip/hip_runtime.h>
#include <math.h>

// ---------------------------------------------------------------------------
// GCN forward: 2 sparse aggregations (CSR, built on-device) + dense GEMMs.
// R3: both dense GEMMs (128x128 hidden, 128x256 fused heads) moved to bf16
//     MFMA (fp32 accum). Weights pre-packed to fragment layout on-device.
// ---------------------------------------------------------------------------

typedef short short8 __attribute__((ext_vector_type(8)));
typedef short short4v __attribute__((ext_vector_type(4)));
typedef float f32x4 __attribute__((ext_vector_type(4)));

static __device__ __forceinline__ short f2bf(float x) {  // RNE fp32->bf16
  unsigned u = __float_as_uint(x);
  u += 0x7fff + ((u >> 16) & 1);
  return (short)(u >> 16);
}

// ---- zero int buffer ------------------------------------------------------
__global__ void k_zero(int* __restrict__ p, int n) {
  int i = blockIdx.x * blockDim.x + threadIdx.x;
  if (i < n) p[i] = 0;
}

// ---- degree count (in-degree over dst) ------------------------------------
__global__ void k_deg(const int* __restrict__ dst, int E, int* __restrict__ deg) {
  int e = blockIdx.x * blockDim.x + threadIdx.x;
  if (e < E) atomicAdd(&deg[dst[e]], 1);
}

// ---- 3-kernel exclusive scan over N ints ----------------------------------
__global__ void k_scan1(const int* __restrict__ deg, int n,
                        int* __restrict__ excl, int* __restrict__ bsum) {
  __shared__ int sm[256];
  int i = blockIdx.x * 256 + threadIdx.x;
  int v = (i < n) ? deg[i] : 0;
  sm[threadIdx.x] = v;
  __syncthreads();
#pragma unroll
  for (int o = 1; o < 256; o <<= 1) {
    int t = (threadIdx.x >= o) ? sm[threadIdx.x - o] : 0;
    __syncthreads();
    sm[threadIdx.x] += t;
    __syncthreads();
  }
  if (i < n) excl[i] = sm[threadIdx.x] - v;
  if (threadIdx.x == 255) bsum[blockIdx.x] = sm[255];
}

__global__ void k_scan2(int* __restrict__ bsum, int nb) {
  __shared__ int sm[256];
  int v = (threadIdx.x < nb) ? bsum[threadIdx.x] : 0;
  sm[threadIdx.x] = v;
  __syncthreads();
#pragma unroll
  for (int o = 1; o < 256; o <<= 1) {
    int t = (threadIdx.x >= o) ? sm[threadIdx.x - o] : 0;
    __syncthreads();
    sm[threadIdx.x] += t;
    __syncthreads();
  }
  if (threadIdx.x < nb) bsum[threadIdx.x] = sm[threadIdx.x] - v;  // exclusive
}

__global__ void k_finalize(int* __restrict__ row_off, const int* __restrict__ bsum,
                           const int* __restrict__ deg, int* __restrict__ cursor,
                           float* __restrict__ dinv, int n) {
  int i = blockIdx.x * 256 + threadIdx.x;
  if (i < n) {
    int ro = row_off[i] + bsum[blockIdx.x];
    row_off[i] = ro;
    cursor[i] = ro;
    dinv[i] = rsqrtf((float)(deg[i] + 1));  // +1 self-loop
  }
}

// ---- CSR fill -------------------------------------------------------------
__global__ void k_fill(const int* __restrict__ src, const int* __restrict__ dst,
                       int E, int* __restrict__ cursor, int* __restrict__ csr) {
  int e = blockIdx.x * blockDim.x + threadIdx.x;
  if (e < E) {
    int d = dst[e];
    int p = atomicAdd(&cursor[d], 1);
    csr[p] = src[e];
  }
}

// ---- row pre-scale: Y[i][:] = dinv[i] * X[i][:] ---------------------------
__global__ __launch_bounds__(256) void k_scale(
    const float* __restrict__ X, const float* __restrict__ dinv,
    float* __restrict__ Y, int n) {
  int t = blockIdx.x * 256 + threadIdx.x;
  int total = n * 32;  // float4s
  if (t < total) {
    int row = t >> 5;
    float d = dinv[row];
    float4 v = reinterpret_cast<const float4*>(X)[t];
    v.x *= d; v.y *= d; v.z *= d; v.w *= d;
    reinterpret_cast<float4*>(Y)[t] = v;
  }
}

// ---- aggregation on pre-scaled rows: out[i] = dinv[i]*( sum_s Y[s] + Y[i] )
__global__ __launch_bounds__(256) void k_agg(
    const float* __restrict__ Y, float* __restrict__ out,
    const int* __restrict__ row_off, const int* __restrict__ deg,
    const int* __restrict__ csr, const float* __restrict__ dinv, int n) {
  int wave = threadIdx.x >> 6;
  int lane = threadIdx.x & 63;
  int i = blockIdx.x * 4 + wave;
  if (i >= n) return;
  int start = row_off[i];
  int cnt = deg[i];
  const float2* Yf2 = reinterpret_cast<const float2*>(Y);
  float ax = 0.f, ay = 0.f;
  int j = 0;
  for (; j + 3 < cnt; j += 4) {
    int s0 = csr[start + j];
    int s1 = csr[start + j + 1];
    int s2 = csr[start + j + 2];
    int s3 = csr[start + j + 3];
    float2 v0 = Yf2[(size_t)s0 * 64 + lane];
    float2 v1 = Yf2[(size_t)s1 * 64 + lane];
    float2 v2 = Yf2[(size_t)s2 * 64 + lane];
    float2 v3 = Yf2[(size_t)s3 * 64 + lane];
    ax += (v0.x + v1.x) + (v2.x + v3.x);
    ay += (v0.y + v1.y) + (v2.y + v3.y);
  }
  for (; j < cnt; ++j) {
    int s0 = csr[start + j];
    float2 v0 = Yf2[(size_t)s0 * 64 + lane];
    ax += v0.x;
    ay += v0.y;
  }
  float2 vs = Yf2[(size_t)i * 64 + lane];
  float di = dinv[i];
  float2 r;
  r.x = (ax + vs.x) * di;
  r.y = (ay + vs.y) * di;
  reinterpret_cast<float2*>(out)[(size_t)i * 64 + lane] = r;
}

// ---- pack W1 [128][128] fp32 -> bf16 fragment layout [(k>>3)][col][k&7] ---
__global__ void k_pack128(const float* __restrict__ W, short* __restrict__ P) {
  int t = blockIdx.x * 256 + threadIdx.x;  // 16384
  int i = t >> 7, c = t & 127;
  P[((i >> 3) * 128 + c) * 8 + (i & 7)] = f2bf(W[t]);
}

// ---- fuse head weights into bf16 packed Wf --------------------------------
// cols: [0,20)=Wt@Wct, [20,50)=Ws@Wcs, [50,250)=Wa@Wca, [250,256)=0.
// packed layout: P[((i>>3)*256 + c)*8 + (i&7)], i = k-row 0..127.
__global__ void k_fuse(const float* __restrict__ Wt, const float* __restrict__ bt,
                       const float* __restrict__ Wct, const float* __restrict__ bct,
                       const float* __restrict__ Ws, const float* __restrict__ bs,
                       const float* __restrict__ Wcs, const float* __restrict__ bcs,
                       const float* __restrict__ Wa, const float* __restrict__ ba,
                       const float* __restrict__ Wca, const float* __restrict__ bca,
                       short* __restrict__ WfPk, float* __restrict__ bf) {
  int c = blockIdx.x;   // 0..255
  int i = threadIdx.x;  // 0..127
  float acc = 0.f, bacc = 0.f;
  if (c < 20) {
    for (int k = 0; k < 20; ++k) {
      float w2 = Wct[k * 20 + c];
      acc += Wt[i * 20 + k] * w2;
      bacc += bt[k] * w2;
    }
    bacc += bct[c];
  } else if (c < 50) {
    int cc = c - 20;
    for (int k = 0; k < 30; ++k) {
      float w2 = Wcs[k * 30 + cc];
      acc += Ws[i * 30 + k] * w2;
      bacc += bs[k] * w2;
    }
    bacc += bcs[cc];
  } else if (c < 250) {
    int cc = c - 50;
    for (int k = 0; k < 200; ++k) {
      float w2 = Wca[k * 200 + cc];
      acc += Wa[i * 200 + k] * w2;
      bacc += ba[k] * w2;
    }
    bacc += bca[cc];
  }
  WfPk[((i >> 3) * 256 + c) * 8 + (i & 7)] = f2bf(acc);
  if (i == 0) bf[c] = bacc;
}

// ---- MFMA GEMM: out[n][NC] = epi(A[n][128] @ Wpk + bias) ------------------
// block 256 = 4 waves; 64 rows/block (16/wave). A staged fp32->bf16 in LDS.
// a-frag: lane holds A[r0+(l&15)][kk*32+(l>>4)*8 + 0..7]
// b-frag: lane holds W[kk*32+(l>>4)*8 + 0..7][t*16+(l&15)]  (packed 16B/lane)
// D tile: col = t*16+(l&15), row = r0+(l>>4)*4+reg.
template <int NC>
__global__ __launch_bounds__(256) void k_mfma_gemm(
    const float* __restrict__ A, const short* __restrict__ Wpk,
    const float* __restrict__ bias, const float* __restrict__ dinv,
    float* __restrict__ out, int n, int relu_dinv) {
  __shared__ short sAb[64][136];  // +16B row pad -> 2-way (free) LDS pattern
  int rowBase = blockIdx.x * 64;
  for (int t = threadIdx.x; t < 64 * 32; t += 256) {
    int r = t >> 5, c4 = t & 31;
    int gr = rowBase + r;
    float4 v = (gr < n) ? reinterpret_cast<const float4*>(A)[(size_t)gr * 32 + c4]
                        : make_float4(0.f, 0.f, 0.f, 0.f);
    short4v s;
    s.x = f2bf(v.x); s.y = f2bf(v.y); s.z = f2bf(v.z); s.w = f2bf(v.w);
    *reinterpret_cast<short4v*>(&sAb[r][c4 * 4]) = s;
  }
  __syncthreads();
  int wave = threadIdx.x >> 6, lane = threadIdx.x & 63;
  int lr = lane & 15, lg = lane >> 4;
  int r0 = wave * 16;
  short8 afr[4];
#pragma unroll
  for (int kk = 0; kk < 4; ++kk)
    afr[kk] = *reinterpret_cast<const short8*>(&sAb[r0 + lr][kk * 32 + lg * 8]);
  f32x4 acc[NC / 16];
#pragma unroll
  for (int t = 0; t < NC / 16; ++t) acc[t] = (f32x4){0.f, 0.f, 0.f, 0.f};
  const short8* Wp8 = reinterpret_cast<const short8*>(Wpk);
#pragma unroll
  for (int t = 0; t < NC / 16; ++t) {
#pragma unroll
    for (int kk = 0; kk < 4; ++kk) {
      short8 bfr = Wp8[(kk * 4 + lg) * NC + t * 16 + lr];
      acc[t] = __builtin_amdgcn_mfma_f32_16x16x32_bf16(afr[kk], bfr, acc[t], 0, 0, 0);
    }
  }
  int rloc = rowBase + r0 + lg * 4;
#pragma unroll
  for (int t = 0; t < NC / 16; ++t) {
    int col = t * 16 + lr;
    float b = bias[col];
#pragma unroll
    for (int reg = 0; reg < 4; ++reg) {
      int row = rloc + reg;
      if (row < n) {
        float v = acc[t][reg] + b;
        if (relu_dinv) v = fmaxf(v, 0.f) * dinv[row];
        out[(size_t)row * NC + col] = v;
      }
    }
  }
}

// ---- segmented softmax over logits: one WAVE per row ----------------------
__global__ __launch_bounds__(256) void k_softmax3(
    const float* __restrict__ L, float* __restrict__ out, int n) {
  int wave = threadIdx.x >> 6, lane = threadIdx.x & 63;
  int r = blockIdx.x * 4 + wave;
  if (r >= n) return;
  float4 v4 = reinterpret_cast<const float4*>(L)[(size_t)r * 64 + lane];
  float v[4] = {v4.x, v4.y, v4.z, v4.w};
  int c0 = lane * 4;
  float mT = -INFINITY, mS = -INFINITY, mA = -INFINITY;
#pragma unroll
  for (int q = 0; q < 4; ++q) {
    int c = c0 + q;
    if (c < 20) mT = fmaxf(mT, v[q]);
    else if (c < 50) mS = fmaxf(mS, v[q]);
    else if (c < 250) mA = fmaxf(mA, v[q]);
  }
#pragma unroll
  for (int o = 32; o; o >>= 1) {
    mT = fmaxf(mT, __shfl_xor(mT, o, 64));
    mS = fmaxf(mS, __shfl_xor(mS, o, 64));
    mA = fmaxf(mA, __shfl_xor(mA, o, 64));
  }
  float e[4];
  float sT = 0.f, sS = 0.f, sA = 0.f;
#pragma unroll
  for (int q = 0; q < 4; ++q) {
    int c = c0 + q;
    float m = (c < 20) ? mT : (c < 50) ? mS : mA;
    float ex = __expf(v[q] - m);
    e[q] = ex;
    if (c < 20) sT += ex;
    else if (c < 50) sS += ex;
    else if (c < 250) sA += ex;
  }
#pragma unroll
  for (int o = 32; o; o >>= 1) {
    sT += __shfl_xor(sT, o, 64);
    sS += __shfl_xor(sS, o, 64);
    sA += __shfl_xor(sA, o, 64);
  }
  float iT = 1.f / sT, iS = 1.f / sS, iA = 1.f / sA;
  float* outT = out;
  float* outS = out + (size_t)n * 20;
  float* outA = out + (size_t)n * 65;
#pragma unroll
  for (int q = 0; q < 4; ++q) {
    int c = c0 + q;
    if (c < 20) outT[(size_t)r * 20 + c] = e[q] * iT;
    else if (c < 50) outS[(size_t)r * 30 + (c - 20)] = e[q] * iS;
    else if (c < 250) outA[(size_t)r * 200 + (c - 50)] = e[q] * iA;
  }
}

// ---- time head: softmax(x0 @ Wtf + btf) -----------------------------------
__global__ __launch_bounds__(256) void k_time(
    const float* __restrict__ x0, const float* __restrict__ Wtf,
    const float* __restrict__ btf, float* __restrict__ outT, int n) {
  __shared__ float sW[128][16];
  __shared__ float sb[16];
  for (int t = threadIdx.x; t < 128 * 16; t += 256) {
    int k = t >> 4, j = t & 15;
    sW[k][j] = (j < 15) ? Wtf[k * 15 + j] : 0.f;
  }
  if (threadIdx.x < 16) sb[threadIdx.x] = (threadIdx.x < 15) ? btf[threadIdx.x] : 0.f;
  __syncthreads();
  int j = threadIdx.x & 15;
  int rl = threadIdx.x >> 4;
  int r = blockIdx.x * 16 + rl;
  if (r >= n) return;
  float acc = sb[j];
  const float4* xr = reinterpret_cast<const float4*>(x0 + (size_t)r * 128);
  for (int k4 = 0; k4 < 32; ++k4) {
    float4 xv = xr[k4];
    acc += xv.x * sW[k4 * 4 + 0][j] + xv.y * sW[k4 * 4 + 1][j] +
           xv.z * sW[k4 * 4 + 2][j] + xv.w * sW[k4 * 4 + 3][j];
  }
  float m = (j < 15) ? acc : -INFINITY;
#pragma unroll
  for (int o = 8; o; o >>= 1) m = fmaxf(m, __shfl_xor(m, o, 16));
  float e = (j < 15) ? __expf(acc - m) : 0.f;
  float s = e;
#pragma unroll
  for (int o = 8; o; o >>= 1) s += __shfl_xor(s, o, 16);
  if (j < 15) outT[(size_t)r * 15 + j] = e / s;
}

// ---------------------------------------------------------------------------
extern "C" void kernel_launch(void* const* d_in, const int* in_sizes, int n_in,
                              void* d_out, int out_size, void* d_ws, size_t ws_size,
                              hipStream_t stream) {
  const float* x0 = (const float*)d_in[0];
  const int* ei = (const int*)d_in[1];
  const float* W1 = (const float*)d_in[2];
  const float* b1 = (const float*)d_in[3];
  const float* Wt = (const float*)d_in[4];
  const float* bt = (const float*)d_in[5];
  const float* Ws = (const float*)d_in[6];
  const float* bs = (const float*)d_in[7];
  const float* Wa = (const float*)d_in[8];
  const float* ba = (const float*)d_in[9];
  const float* Wct = (const float*)d_in[10];
  const float* bct = (const float*)d_in[11];
  const float* Wcs = (const float*)d_in[12];
  const float* bcs = (const float*)d_in[13];
  const float* Wtf = (const float*)d_in[14];
  const float* btf = (const float*)d_in[15];
  const float* Wca = (const float*)d_in[16];
  const float* bca = (const float*)d_in[17];
  (void)n_in; (void)out_size; (void)ws_size;

  int N = in_sizes[0] / 128;
  int E = in_sizes[1] / 2;
  float* out = (float*)d_out;

  char* ws = (char*)d_ws;
  size_t off = 0;
  auto alloc = [&](size_t bytes) -> void* {
    void* p = ws + off;
    off = (off + bytes + 255) & ~(size_t)255;
    return p;
  };
  int* deg = (int*)alloc((size_t)N * 4);
  int* row_off = (int*)alloc((size_t)N * 4);
  int* bsum = (int*)alloc(256 * 4);
  int* cursor = (int*)alloc((size_t)N * 4);
  float* dinv = (float*)alloc((size_t)N * 4);
  int* csr = (int*)alloc((size_t)E * 4);
  short* WfPk = (short*)alloc((size_t)128 * 256 * 2);
  short* W1Pk = (short*)alloc((size_t)128 * 128 * 2);
  float* bf = (float*)alloc(256 * 4);
  float* A = (float*)alloc((size_t)N * 128 * 4);
  float* B = (float*)alloc((size_t)N * 256 * 4);  // doubles as logits buffer

  const int* srcp = ei;
  const int* dstp = ei + E;
  int gE = (E + 255) / 256;
  int gN = (N + 255) / 256;  // 196 <= 256, required by k_scan2

  k_zero<<<gN, 256, 0, stream>>>(deg, N);
  k_deg<<<gE, 256, 0, stream>>>(dstp, E, deg);
  k_scan1<<<gN, 256, 0, stream>>>(deg, N, row_off, bsum);
  k_scan2<<<1, 256, 0, stream>>>(bsum, gN);
  k_finalize<<<gN, 256, 0, stream>>>(row_off, bsum, deg, cursor, dinv, N);
  k_fill<<<gE, 256, 0, stream>>>(srcp, dstp, E, cursor, csr);
  // weight packing (independent of graph work)
  k_pack128<<<64, 256, 0, stream>>>(W1, W1Pk);
  k_fuse<<<256, 128, 0, stream>>>(Wt, bt, Wct, bct, Ws, bs, Wcs, bcs, Wa, ba, Wca,
                                  bca, WfPk, bf);
  // Y0 = dinv*x0 -> B ; A = agg(Y0)
  k_scale<<<(N * 32 + 255) / 256, 256, 0, stream>>>(x0, dinv, B, N);
  k_agg<<<(N + 3) / 4, 256, 0, stream>>>(B, A, row_off, deg, csr, dinv, N);
  // B = dinv*relu(A@W1+b1)   [MFMA]
  k_mfma_gemm<128><<<(N + 63) / 64, 256, 0, stream>>>(A, W1Pk, b1, dinv, B, N, 1);
  // A = agg(B)
  k_agg<<<(N + 3) / 4, 256, 0, stream>>>(B, A, row_off, deg, csr, dinv, N);
  // L = A @ Wf + bf  (B reused as logits)   [MFMA]
  k_mfma_gemm<256><<<(N + 63) / 64, 256, 0, stream>>>(A, WfPk, bf, dinv, B, N, 0);
  k_softmax3<<<(N + 3) / 4, 256, 0, stream>>>(B, out, N);
  k_time<<<(N + 15) / 16, 256, 0, stream>>>(x0, Wtf, btf, out + (size_t)N * 50, N);
}

// Round 5
// 388.673 us; speedup vs baseline: 1.7689x; 1.1163x over previous
//
#include <hip/hip_runtime.h>
#include <math.h>

// ---------------------------------------------------------------------------
// GCN forward. R4: whole node-feature pipeline in bf16 tables (fp32 accum):
// halves gather/staging traffic. Segmented softmax fused into heads MFMA GEMM
// (no logits round-trip). Setup: CSR built on-device (int atomics + scan).
// ---------------------------------------------------------------------------

typedef short short8 __attribute__((ext_vector_type(8)));
typedef float f32x4 __attribute__((ext_vector_type(4)));

static __device__ __forceinline__ unsigned short f2bf(float x) {  // RNE
  unsigned u = __float_as_uint(x);
  u += 0x7fff + ((u >> 16) & 1);
  return (unsigned short)(u >> 16);
}
static __device__ __forceinline__ unsigned pack2bf(float lo, float hi) {
  return ((unsigned)f2bf(hi) << 16) | (unsigned)f2bf(lo);
}
static __device__ __forceinline__ float bflo(unsigned u) {
  return __uint_as_float(u << 16);
}
static __device__ __forceinline__ float bfhi(unsigned u) {
  return __uint_as_float(u & 0xffff0000u);
}

// ---- zero int buffer ------------------------------------------------------
__global__ void k_zero(int* __restrict__ p, int n) {
  int i = blockIdx.x * blockDim.x + threadIdx.x;
  if (i < n) p[i] = 0;
}

// ---- degree count (in-degree over dst) ------------------------------------
__global__ void k_deg(const int* __restrict__ dst, int E, int* __restrict__ deg) {
  int e = blockIdx.x * blockDim.x + threadIdx.x;
  if (e < E) atomicAdd(&deg[dst[e]], 1);
}

// ---- 3-kernel exclusive scan over N ints ----------------------------------
__global__ void k_scan1(const int* __restrict__ deg, int n,
                        int* __restrict__ excl, int* __restrict__ bsum) {
  __shared__ int sm[256];
  int i = blockIdx.x * 256 + threadIdx.x;
  int v = (i < n) ? deg[i] : 0;
  sm[threadIdx.x] = v;
  __syncthreads();
#pragma unroll
  for (int o = 1; o < 256; o <<= 1) {
    int t = (threadIdx.x >= o) ? sm[threadIdx.x - o] : 0;
    __syncthreads();
    sm[threadIdx.x] += t;
    __syncthreads();
  }
  if (i < n) excl[i] = sm[threadIdx.x] - v;
  if (threadIdx.x == 255) bsum[blockIdx.x] = sm[255];
}

__global__ void k_scan2(int* __restrict__ bsum, int nb) {
  __shared__ int sm[256];
  int v = (threadIdx.x < nb) ? bsum[threadIdx.x] : 0;
  sm[threadIdx.x] = v;
  __syncthreads();
#pragma unroll
  for (int o = 1; o < 256; o <<= 1) {
    int t = (threadIdx.x >= o) ? sm[threadIdx.x - o] : 0;
    __syncthreads();
    sm[threadIdx.x] += t;
    __syncthreads();
  }
  if (threadIdx.x < nb) bsum[threadIdx.x] = sm[threadIdx.x] - v;  // exclusive
}

__global__ void k_finalize(int* __restrict__ row_off, const int* __restrict__ bsum,
                           const int* __restrict__ deg, int* __restrict__ cursor,
                           float* __restrict__ dinv, int n) {
  int i = blockIdx.x * 256 + threadIdx.x;
  if (i < n) {
    int ro = row_off[i] + bsum[blockIdx.x];
    row_off[i] = ro;
    cursor[i] = ro;
    dinv[i] = rsqrtf((float)(deg[i] + 1));  // +1 self-loop
  }
}

// ---- CSR fill -------------------------------------------------------------
__global__ void k_fill(const int* __restrict__ src, const int* __restrict__ dst,
                       int E, int* __restrict__ cursor, int* __restrict__ csr) {
  int e = blockIdx.x * blockDim.x + threadIdx.x;
  if (e < E) {
    int d = dst[e];
    int p = atomicAdd(&cursor[d], 1);
    csr[p] = src[e];
  }
}

// ---- row pre-scale -> bf16: Y[i][:] = bf16(dinv[i] * X[i][:]) -------------
__global__ __launch_bounds__(256) void k_scale(
    const float* __restrict__ X, const float* __restrict__ dinv,
    unsigned* __restrict__ Y, int n) {
  int t = blockIdx.x * 256 + threadIdx.x;  // one uint (2 cols) per thread
  int total = n * 64;
  if (t < total) {
    int row = t >> 6;
    float d = dinv[row];
    float2 v = reinterpret_cast<const float2*>(X)[t];
    Y[t] = pack2bf(v.x * d, v.y * d);
  }
}

// ---- aggregation on bf16 tables: out[i] = bf16(dinv[i]*(sum_s Y[s] + Y[i]))
// one wave per node; lane holds one uint (2 bf16 cols); fp32 accum.
__global__ __launch_bounds__(256) void k_agg(
    const unsigned* __restrict__ Y, unsigned* __restrict__ out,
    const int* __restrict__ row_off, const int* __restrict__ deg,
    const int* __restrict__ csr, const float* __restrict__ dinv, int n) {
  int wave = threadIdx.x >> 6;
  int lane = threadIdx.x & 63;
  int i = blockIdx.x * 4 + wave;
  if (i >= n) return;
  int start = row_off[i];
  int cnt = deg[i];
  float ax = 0.f, ay = 0.f;
  int j = 0;
  for (; j + 3 < cnt; j += 4) {
    int s0 = csr[start + j];
    int s1 = csr[start + j + 1];
    int s2 = csr[start + j + 2];
    int s3 = csr[start + j + 3];
    unsigned u0 = Y[(size_t)s0 * 64 + lane];
    unsigned u1 = Y[(size_t)s1 * 64 + lane];
    unsigned u2 = Y[(size_t)s2 * 64 + lane];
    unsigned u3 = Y[(size_t)s3 * 64 + lane];
    ax += (bflo(u0) + bflo(u1)) + (bflo(u2) + bflo(u3));
    ay += (bfhi(u0) + bfhi(u1)) + (bfhi(u2) + bfhi(u3));
  }
  for (; j < cnt; ++j) {
    int s0 = csr[start + j];
    unsigned u0 = Y[(size_t)s0 * 64 + lane];
    ax += bflo(u0);
    ay += bfhi(u0);
  }
  unsigned us = Y[(size_t)i * 64 + lane];
  float di = dinv[i];
  out[(size_t)i * 64 + lane] = pack2bf((ax + bflo(us)) * di, (ay + bfhi(us)) * di);
}

// ---- pack W1 [128][128] fp32 -> bf16 fragment layout [(k>>3)][col][k&7] ---
__global__ void k_pack128(const float* __restrict__ W, unsigned short* __restrict__ P) {
  int t = blockIdx.x * 256 + threadIdx.x;  // 16384
  int i = t >> 7, c = t & 127;
  P[((i >> 3) * 128 + c) * 8 + (i & 7)] = f2bf(W[t]);
}

// ---- fuse head weights into bf16 packed Wf --------------------------------
__global__ void k_fuse(const float* __restrict__ Wt, const float* __restrict__ bt,
                       const float* __restrict__ Wct, const float* __restrict__ bct,
                       const float* __restrict__ Ws, const float* __restrict__ bs,
                       const float* __restrict__ Wcs, const float* __restrict__ bcs,
                       const float* __restrict__ Wa, const float* __restrict__ ba,
                       const float* __restrict__ Wca, const float* __restrict__ bca,
                       unsigned short* __restrict__ WfPk, float* __restrict__ bf) {
  int c = blockIdx.x;   // 0..255
  int i = threadIdx.x;  // 0..127
  float acc = 0.f, bacc = 0.f;
  if (c < 20) {
    for (int k = 0; k < 20; ++k) {
      float w2 = Wct[k * 20 + c];
      acc += Wt[i * 20 + k] * w2;
      bacc += bt[k] * w2;
    }
    bacc += bct[c];
  } else if (c < 50) {
    int cc = c - 20;
    for (int k = 0; k < 30; ++k) {
      float w2 = Wcs[k * 30 + cc];
      acc += Ws[i * 30 + k] * w2;
      bacc += bs[k] * w2;
    }
    bacc += bcs[cc];
  } else if (c < 250) {
    int cc = c - 50;
    for (int k = 0; k < 200; ++k) {
      float w2 = Wca[k * 200 + cc];
      acc += Wa[i * 200 + k] * w2;
      bacc += ba[k] * w2;
    }
    bacc += bca[cc];
  }
  WfPk[((i >> 3) * 256 + c) * 8 + (i & 7)] = f2bf(acc);
  if (i == 0) bf[c] = bacc;
}

// ---- shared staging: 64 bf16 rows of A into LDS ---------------------------
static __device__ __forceinline__ void stage_rows(
    const short* __restrict__ A, short (*sAb)[136], int rowBase, int n, int tid) {
  for (int t = tid; t < 64 * 16; t += 256) {  // 1024 short8 chunks
    int r = t >> 4, c8 = t & 15;
    int gr = rowBase + r;
    short8 v;
    if (gr < n)
      v = *reinterpret_cast<const short8*>(A + (size_t)gr * 128 + c8 * 8);
    else
      v = (short8){0, 0, 0, 0, 0, 0, 0, 0};
    *reinterpret_cast<short8*>(&sAb[r][c8 * 8]) = v;
  }
}

// ---- MFMA GEMM 128x128: out = bf16(dinv[r]*relu(A@W1 + b)) ----------------
__global__ __launch_bounds__(256) void k_mfma_gemm128(
    const short* __restrict__ A, const unsigned short* __restrict__ Wpk,
    const float* __restrict__ bias, const float* __restrict__ dinv,
    unsigned short* __restrict__ out, int n) {
  __shared__ short sAb[64][136];
  int rowBase = blockIdx.x * 64;
  stage_rows(A, sAb, rowBase, n, threadIdx.x);
  __syncthreads();
  int wave = threadIdx.x >> 6, lane = threadIdx.x & 63;
  int lr = lane & 15, lg = lane >> 4;
  int r0 = wave * 16;
  short8 afr[4];
#pragma unroll
  for (int kk = 0; kk < 4; ++kk)
    afr[kk] = *reinterpret_cast<const short8*>(&sAb[r0 + lr][kk * 32 + lg * 8]);
  f32x4 acc[8];
#pragma unroll
  for (int t = 0; t < 8; ++t) acc[t] = (f32x4){0.f, 0.f, 0.f, 0.f};
  const short8* Wp8 = reinterpret_cast<const short8*>(Wpk);
#pragma unroll
  for (int t = 0; t < 8; ++t) {
#pragma unroll
    for (int kk = 0; kk < 4; ++kk) {
      short8 bfr = Wp8[(kk * 4 + lg) * 128 + t * 16 + lr];
      acc[t] = __builtin_amdgcn_mfma_f32_16x16x32_bf16(afr[kk], bfr, acc[t], 0, 0, 0);
    }
  }
  int rloc = rowBase + r0 + lg * 4;
#pragma unroll
  for (int t = 0; t < 8; ++t) {
    int col = t * 16 + lr;
    float b = bias[col];
#pragma unroll
    for (int reg = 0; reg < 4; ++reg) {
      int row = rloc + reg;
      if (row < n) {
        float v = fmaxf(acc[t][reg] + b, 0.f) * dinv[row];
        out[(size_t)row * 128 + col] = f2bf(v);
      }
    }
  }
}

// ---- heads: MFMA GEMM 128x256 + fused segmented softmax -> 3 outputs ------
// acc layout: col = t*16+lr, row = rloc + reg. Per-row reduce = 16 regs (t)
// in-register + 4-step shfl over the 16-lane (lr) group.
__global__ __launch_bounds__(256) void k_heads_fused(
    const short* __restrict__ A, const unsigned short* __restrict__ Wpk,
    const float* __restrict__ bf, float* __restrict__ outT,
    float* __restrict__ outS, float* __restrict__ outA, int n) {
  __shared__ short sAb[64][136];
  int rowBase = blockIdx.x * 64;
  stage_rows(A, sAb, rowBase, n, threadIdx.x);
  __syncthreads();
  int wave = threadIdx.x >> 6, lane = threadIdx.x & 63;
  int lr = lane & 15, lg = lane >> 4;
  int r0 = wave * 16;
  short8 afr[4];
#pragma unroll
  for (int kk = 0; kk < 4; ++kk)
    afr[kk] = *reinterpret_cast<const short8*>(&sAb[r0 + lr][kk * 32 + lg * 8]);
  f32x4 acc[16];
#pragma unroll
  for (int t = 0; t < 16; ++t) acc[t] = (f32x4){0.f, 0.f, 0.f, 0.f};
  const short8* Wp8 = reinterpret_cast<const short8*>(Wpk);
#pragma unroll
  for (int t = 0; t < 16; ++t) {
#pragma unroll
    for (int kk = 0; kk < 4; ++kk) {
      short8 bfr = Wp8[(kk * 4 + lg) * 256 + t * 16 + lr];
      acc[t] = __builtin_amdgcn_mfma_f32_16x16x32_bf16(afr[kk], bfr, acc[t], 0, 0, 0);
    }
  }
  float bias_l[16];
#pragma unroll
  for (int t = 0; t < 16; ++t) bias_l[t] = bf[t * 16 + lr];
  int rloc = rowBase + r0 + lg * 4;
#pragma unroll
  for (int reg = 0; reg < 4; ++reg) {
    int row = rloc + reg;
    float v[16];
    float mT = -INFINITY, mS = -INFINITY, mA = -INFINITY;
#pragma unroll
    for (int t = 0; t < 16; ++t) {
      v[t] = acc[t][reg] + bias_l[t];
      int c = t * 16 + lr;
      if (c < 20) mT = fmaxf(mT, v[t]);
      else if (c < 50) mS = fmaxf(mS, v[t]);
      else if (c < 250) mA = fmaxf(mA, v[t]);
    }
#pragma unroll
    for (int o = 8; o; o >>= 1) {
      mT = fmaxf(mT, __shfl_xor(mT, o, 64));
      mS = fmaxf(mS, __shfl_xor(mS, o, 64));
      mA = fmaxf(mA, __shfl_xor(mA, o, 64));
    }
    float sT = 0.f, sS = 0.f, sA = 0.f;
#pragma unroll
    for (int t = 0; t < 16; ++t) {
      int c = t * 16 + lr;
      float m = (c < 20) ? mT : (c < 50) ? mS : mA;
      float ex = __expf(v[t] - m);
      v[t] = ex;
      if (c < 20) sT += ex;
      else if (c < 50) sS += ex;
      else if (c < 250) sA += ex;
    }
#pragma unroll
    for (int o = 8; o; o >>= 1) {
      sT += __shfl_xor(sT, o, 64);
      sS += __shfl_xor(sS, o, 64);
      sA += __shfl_xor(sA, o, 64);
    }
    float iT = 1.f / sT, iS = 1.f / sS, iA = 1.f / sA;
    if (row < n) {
#pragma unroll
      for (int t = 0; t < 16; ++t) {
        int c = t * 16 + lr;
        if (c < 20) outT[(size_t)row * 20 + c] = v[t] * iT;
        else if (c < 50) outS[(size_t)row * 30 + (c - 20)] = v[t] * iS;
        else if (c < 250) outA[(size_t)row * 200 + (c - 50)] = v[t] * iA;
      }
    }
  }
}

// ---- time head: softmax(x0 @ Wtf + btf) -----------------------------------
__global__ __launch_bounds__(256) void k_time(
    const float* __restrict__ x0, const float* __restrict__ Wtf,
    const float* __restrict__ btf, float* __restrict__ outT, int n) {
  __shared__ float sW[128][16];
  __shared__ float sb[16];
  for (int t = threadIdx.x; t < 128 * 16; t += 256) {
    int k = t >> 4, j = t & 15;
    sW[k][j] = (j < 15) ? Wtf[k * 15 + j] : 0.f;
  }
  if (threadIdx.x < 16) sb[threadIdx.x] = (threadIdx.x < 15) ? btf[threadIdx.x] : 0.f;
  __syncthreads();
  int j = threadIdx.x & 15;
  int rl = threadIdx.x >> 4;
  int r = blockIdx.x * 16 + rl;
  if (r >= n) return;
  float acc = sb[j];
  const float4* xr = reinterpret_cast<const float4*>(x0 + (size_t)r * 128);
  for (int k4 = 0; k4 < 32; ++k4) {
    float4 xv = xr[k4];
    acc += xv.x * sW[k4 * 4 + 0][j] + xv.y * sW[k4 * 4 + 1][j] +
           xv.z * sW[k4 * 4 + 2][j] + xv.w * sW[k4 * 4 + 3][j];
  }
  float m = (j < 15) ? acc : -INFINITY;
#pragma unroll
  for (int o = 8; o; o >>= 1) m = fmaxf(m, __shfl_xor(m, o, 16));
  float e = (j < 15) ? __expf(acc - m) : 0.f;
  float s = e;
#pragma unroll
  for (int o = 8; o; o >>= 1) s += __shfl_xor(s, o, 16);
  if (j < 15) outT[(size_t)r * 15 + j] = e / s;
}

// ---------------------------------------------------------------------------
extern "C" void kernel_launch(void* const* d_in, const int* in_sizes, int n_in,
                              void* d_out, int out_size, void* d_ws, size_t ws_size,
                              hipStream_t stream) {
  const float* x0 = (const float*)d_in[0];
  const int* ei = (const int*)d_in[1];
  const float* W1 = (const float*)d_in[2];
  const float* b1 = (const float*)d_in[3];
  const float* Wt = (const float*)d_in[4];
  const float* bt = (const float*)d_in[5];
  const float* Ws = (const float*)d_in[6];
  const float* bs = (const float*)d_in[7];
  const float* Wa = (const float*)d_in[8];
  const float* ba = (const float*)d_in[9];
  const float* Wct = (const float*)d_in[10];
  const float* bct = (const float*)d_in[11];
  const float* Wcs = (const float*)d_in[12];
  const float* bcs = (const float*)d_in[13];
  const float* Wtf = (const float*)d_in[14];
  const float* btf = (const float*)d_in[15];
  const float* Wca = (const float*)d_in[16];
  const float* bca = (const float*)d_in[17];
  (void)n_in; (void)out_size; (void)ws_size;

  int N = in_sizes[0] / 128;
  int E = in_sizes[1] / 2;
  float* out = (float*)d_out;

  char* ws = (char*)d_ws;
  size_t off = 0;
  auto alloc = [&](size_t bytes) -> void* {
    void* p = ws + off;
    off = (off + bytes + 255) & ~(size_t)255;
    return p;
  };
  int* deg = (int*)alloc((size_t)N * 4);
  int* row_off = (int*)alloc((size_t)N * 4);
  int* bsum = (int*)alloc(256 * 4);
  int* cursor = (int*)alloc((size_t)N * 4);
  float* dinv = (float*)alloc((size_t)N * 4);
  int* csr = (int*)alloc((size_t)E * 4);
  unsigned short* WfPk = (unsigned short*)alloc((size_t)128 * 256 * 2);
  unsigned short* W1Pk = (unsigned short*)alloc((size_t)128 * 128 * 2);
  float* bf = (float*)alloc(256 * 4);
  unsigned* Yb = (unsigned*)alloc((size_t)N * 64 * 4);  // bf16 table (pre-scaled x0)
  unsigned* Ab = (unsigned*)alloc((size_t)N * 64 * 4);  // bf16 table (agg results)
  unsigned* Bb = (unsigned*)alloc((size_t)N * 64 * 4);  // bf16 table (hidden)

  const int* srcp = ei;
  const int* dstp = ei + E;
  int gE = (E + 255) / 256;
  int gN = (N + 255) / 256;  // 196 <= 256, required by k_scan2

  k_zero<<<gN, 256, 0, stream>>>(deg, N);
  k_deg<<<gE, 256, 0, stream>>>(dstp, E, deg);
  k_scan1<<<gN, 256, 0, stream>>>(deg, N, row_off, bsum);
  k_scan2<<<1, 256, 0, stream>>>(bsum, gN);
  k_finalize<<<gN, 256, 0, stream>>>(row_off, bsum, deg, cursor, dinv, N);
  k_fill<<<gE, 256, 0, stream>>>(srcp, dstp, E, cursor, csr);
  // weight packing (independent of graph work)
  k_pack128<<<64, 256, 0, stream>>>(W1, W1Pk);
  k_fuse<<<256, 128, 0, stream>>>(Wt, bt, Wct, bct, Ws, bs, Wcs, bcs, Wa, ba, Wca,
                                  bca, WfPk, bf);
  // Yb = bf16(dinv*x0) ; Ab = agg(Yb)
  k_scale<<<(N * 64 + 255) / 256, 256, 0, stream>>>(x0, dinv, Yb, N);
  k_agg<<<(N + 3) / 4, 256, 0, stream>>>(Yb, Ab, row_off, deg, csr, dinv, N);
  // Bb = bf16(dinv*relu(Ab@W1+b1))   [MFMA]
  k_mfma_gemm128<<<(N + 63) / 64, 256, 0, stream>>>(
      (const short*)Ab, W1Pk, b1, dinv, (unsigned short*)Bb, N);
  // Ab = agg(Bb)
  k_agg<<<(N + 3) / 4, 256, 0, stream>>>(Bb, Ab, row_off, deg, csr, dinv, N);
  // heads: MFMA + fused segmented softmax
  k_heads_fused<<<(N + 63) / 64, 256, 0, stream>>>(
      (const short*)Ab, WfPk, bf, out, out + (size_t)N * 20, out + (size_t)N * 65, N);
  k_time<<<(N + 15) / 16, 256, 0, stream>>>(x0, Wtf, btf, out + (size_t)N * 50, N);
}

// Round 6
// 381.627 us; speedup vs baseline: 1.8016x; 1.0185x over previous
//
#include <hip/hip_runtime.h>
#include <math.h>

// ---------------------------------------------------------------------------
// GCN forward. R5: MFMA GEMM kernels drop LDS staging + barrier entirely —
// A-fragments read directly from global (L2-resident bf16 tables), all waves
// independent => latency hidden by TLP. Pipeline otherwise as R4 (bf16 tables,
// fused segmented softmax, CSR built on-device).
// ---------------------------------------------------------------------------

typedef short short8 __attribute__((ext_vector_type(8)));
typedef float f32x4 __attribute__((ext_vector_type(4)));

static __device__ __forceinline__ unsigned short f2bf(float x) {  // RNE
  unsigned u = __float_as_uint(x);
  u += 0x7fff + ((u >> 16) & 1);
  return (unsigned short)(u >> 16);
}
static __device__ __forceinline__ unsigned pack2bf(float lo, float hi) {
  return ((unsigned)f2bf(hi) << 16) | (unsigned)f2bf(lo);
}
static __device__ __forceinline__ float bflo(unsigned u) {
  return __uint_as_float(u << 16);
}
static __device__ __forceinline__ float bfhi(unsigned u) {
  return __uint_as_float(u & 0xffff0000u);
}

// ---- zero int buffer ------------------------------------------------------
__global__ void k_zero(int* __restrict__ p, int n) {
  int i = blockIdx.x * blockDim.x + threadIdx.x;
  if (i < n) p[i] = 0;
}

// ---- degree count (in-degree over dst) ------------------------------------
__global__ void k_deg(const int* __restrict__ dst, int E, int* __restrict__ deg) {
  int e = blockIdx.x * blockDim.x + threadIdx.x;
  if (e < E) atomicAdd(&deg[dst[e]], 1);
}

// ---- 3-kernel exclusive scan over N ints ----------------------------------
__global__ void k_scan1(const int* __restrict__ deg, int n,
                        int* __restrict__ excl, int* __restrict__ bsum) {
  __shared__ int sm[256];
  int i = blockIdx.x * 256 + threadIdx.x;
  int v = (i < n) ? deg[i] : 0;
  sm[threadIdx.x] = v;
  __syncthreads();
#pragma unroll
  for (int o = 1; o < 256; o <<= 1) {
    int t = (threadIdx.x >= o) ? sm[threadIdx.x - o] : 0;
    __syncthreads();
    sm[threadIdx.x] += t;
    __syncthreads();
  }
  if (i < n) excl[i] = sm[threadIdx.x] - v;
  if (threadIdx.x == 255) bsum[blockIdx.x] = sm[255];
}

__global__ void k_scan2(int* __restrict__ bsum, int nb) {
  __shared__ int sm[256];
  int v = (threadIdx.x < nb) ? bsum[threadIdx.x] : 0;
  sm[threadIdx.x] = v;
  __syncthreads();
#pragma unroll
  for (int o = 1; o < 256; o <<= 1) {
    int t = (threadIdx.x >= o) ? sm[threadIdx.x - o] : 0;
    __syncthreads();
    sm[threadIdx.x] += t;
    __syncthreads();
  }
  if (threadIdx.x < nb) bsum[threadIdx.x] = sm[threadIdx.x] - v;  // exclusive
}

__global__ void k_finalize(int* __restrict__ row_off, const int* __restrict__ bsum,
                           const int* __restrict__ deg, int* __restrict__ cursor,
                           float* __restrict__ dinv, int n) {
  int i = blockIdx.x * 256 + threadIdx.x;
  if (i < n) {
    int ro = row_off[i] + bsum[blockIdx.x];
    row_off[i] = ro;
    cursor[i] = ro;
    dinv[i] = rsqrtf((float)(deg[i] + 1));  // +1 self-loop
  }
}

// ---- CSR fill -------------------------------------------------------------
__global__ void k_fill(const int* __restrict__ src, const int* __restrict__ dst,
                       int E, int* __restrict__ cursor, int* __restrict__ csr) {
  int e = blockIdx.x * blockDim.x + threadIdx.x;
  if (e < E) {
    int d = dst[e];
    int p = atomicAdd(&cursor[d], 1);
    csr[p] = src[e];
  }
}

// ---- row pre-scale -> bf16: Y[i][:] = bf16(dinv[i] * X[i][:]) -------------
__global__ __launch_bounds__(256) void k_scale(
    const float* __restrict__ X, const float* __restrict__ dinv,
    unsigned* __restrict__ Y, int n) {
  int t = blockIdx.x * 256 + threadIdx.x;  // one uint (2 cols) per thread
  int total = n * 64;
  if (t < total) {
    int row = t >> 6;
    float d = dinv[row];
    float2 v = reinterpret_cast<const float2*>(X)[t];
    Y[t] = pack2bf(v.x * d, v.y * d);
  }
}

// ---- aggregation on bf16 tables: out[i] = bf16(dinv[i]*(sum_s Y[s] + Y[i]))
// one wave per node; lane holds one uint (2 bf16 cols); fp32 accum.
__global__ __launch_bounds__(256) void k_agg(
    const unsigned* __restrict__ Y, unsigned* __restrict__ out,
    const int* __restrict__ row_off, const int* __restrict__ deg,
    const int* __restrict__ csr, const float* __restrict__ dinv, int n) {
  int wave = threadIdx.x >> 6;
  int lane = threadIdx.x & 63;
  int i = blockIdx.x * 4 + wave;
  if (i >= n) return;
  int start = row_off[i];
  int cnt = deg[i];
  float ax = 0.f, ay = 0.f;
  int j = 0;
  for (; j + 3 < cnt; j += 4) {
    int s0 = csr[start + j];
    int s1 = csr[start + j + 1];
    int s2 = csr[start + j + 2];
    int s3 = csr[start + j + 3];
    unsigned u0 = Y[(size_t)s0 * 64 + lane];
    unsigned u1 = Y[(size_t)s1 * 64 + lane];
    unsigned u2 = Y[(size_t)s2 * 64 + lane];
    unsigned u3 = Y[(size_t)s3 * 64 + lane];
    ax += (bflo(u0) + bflo(u1)) + (bflo(u2) + bflo(u3));
    ay += (bfhi(u0) + bfhi(u1)) + (bfhi(u2) + bfhi(u3));
  }
  for (; j < cnt; ++j) {
    int s0 = csr[start + j];
    unsigned u0 = Y[(size_t)s0 * 64 + lane];
    ax += bflo(u0);
    ay += bfhi(u0);
  }
  unsigned us = Y[(size_t)i * 64 + lane];
  float di = dinv[i];
  out[(size_t)i * 64 + lane] = pack2bf((ax + bflo(us)) * di, (ay + bfhi(us)) * di);
}

// ---- pack W1 [128][128] fp32 -> bf16 fragment layout [(k>>3)][col][k&7] ---
__global__ void k_pack128(const float* __restrict__ W, unsigned short* __restrict__ P) {
  int t = blockIdx.x * 256 + threadIdx.x;  // 16384
  int i = t >> 7, c = t & 127;
  P[((i >> 3) * 128 + c) * 8 + (i & 7)] = f2bf(W[t]);
}

// ---- fuse head weights into bf16 packed Wf --------------------------------
__global__ void k_fuse(const float* __restrict__ Wt, const float* __restrict__ bt,
                       const float* __restrict__ Wct, const float* __restrict__ bct,
                       const float* __restrict__ Ws, const float* __restrict__ bs,
                       const float* __restrict__ Wcs, const float* __restrict__ bcs,
                       const float* __restrict__ Wa, const float* __restrict__ ba,
                       const float* __restrict__ Wca, const float* __restrict__ bca,
                       unsigned short* __restrict__ WfPk, float* __restrict__ bf) {
  int c = blockIdx.x;   // 0..255
  int i = threadIdx.x;  // 0..127
  float acc = 0.f, bacc = 0.f;
  if (c < 20) {
    for (int k = 0; k < 20; ++k) {
      float w2 = Wct[k * 20 + c];
      acc += Wt[i * 20 + k] * w2;
      bacc += bt[k] * w2;
    }
    bacc += bct[c];
  } else if (c < 50) {
    int cc = c - 20;
    for (int k = 0; k < 30; ++k) {
      float w2 = Wcs[k * 30 + cc];
      acc += Ws[i * 30 + k] * w2;
      bacc += bs[k] * w2;
    }
    bacc += bcs[cc];
  } else if (c < 250) {
    int cc = c - 50;
    for (int k = 0; k < 200; ++k) {
      float w2 = Wca[k * 200 + cc];
      acc += Wa[i * 200 + k] * w2;
      bacc += ba[k] * w2;
    }
    bacc += bca[cc];
  }
  WfPk[((i >> 3) * 256 + c) * 8 + (i & 7)] = f2bf(acc);
  if (i == 0) bf[c] = bacc;
}

// ---- MFMA GEMM 128x128, no LDS: out = bf16(dinv[r]*relu(A@W1 + b)) --------
// wave-independent: a-frag rows read directly from global (L2-resident).
__global__ __launch_bounds__(256) void k_mfma_gemm128(
    const short* __restrict__ A, const unsigned short* __restrict__ Wpk,
    const float* __restrict__ bias, const float* __restrict__ dinv,
    unsigned short* __restrict__ out, int n) {
  int wave = threadIdx.x >> 6, lane = threadIdx.x & 63;
  int lr = lane & 15, lg = lane >> 4;
  int r0 = blockIdx.x * 64 + wave * 16;
  if (r0 >= n) return;
  int ar = r0 + lr;
  if (ar >= n) ar = n - 1;  // clamp (extra rows never stored)
  const short* Arow = A + (size_t)ar * 128;
  short8 afr[4];
#pragma unroll
  for (int kk = 0; kk < 4; ++kk)
    afr[kk] = *reinterpret_cast<const short8*>(Arow + kk * 32 + lg * 8);
  f32x4 acc[8];
#pragma unroll
  for (int t = 0; t < 8; ++t) acc[t] = (f32x4){0.f, 0.f, 0.f, 0.f};
  const short8* Wp8 = reinterpret_cast<const short8*>(Wpk);
#pragma unroll
  for (int t = 0; t < 8; ++t) {
#pragma unroll
    for (int kk = 0; kk < 4; ++kk) {
      short8 bfr = Wp8[(kk * 4 + lg) * 128 + t * 16 + lr];
      acc[t] = __builtin_amdgcn_mfma_f32_16x16x32_bf16(afr[kk], bfr, acc[t], 0, 0, 0);
    }
  }
  int rloc = r0 + lg * 4;
#pragma unroll
  for (int t = 0; t < 8; ++t) {
    int col = t * 16 + lr;
    float b = bias[col];
#pragma unroll
    for (int reg = 0; reg < 4; ++reg) {
      int row = rloc + reg;
      if (row < n) {
        float v = fmaxf(acc[t][reg] + b, 0.f) * dinv[row];
        out[(size_t)row * 128 + col] = f2bf(v);
      }
    }
  }
}

// ---- heads: MFMA GEMM 128x256 + fused segmented softmax, no LDS -----------
__global__ __launch_bounds__(256) void k_heads_fused(
    const short* __restrict__ A, const unsigned short* __restrict__ Wpk,
    const float* __restrict__ bf, float* __restrict__ outT,
    float* __restrict__ outS, float* __restrict__ outA, int n) {
  int wave = threadIdx.x >> 6, lane = threadIdx.x & 63;
  int lr = lane & 15, lg = lane >> 4;
  int r0 = blockIdx.x * 64 + wave * 16;
  if (r0 >= n) return;
  int ar = r0 + lr;
  if (ar >= n) ar = n - 1;  // clamp
  const short* Arow = A + (size_t)ar * 128;
  short8 afr[4];
#pragma unroll
  for (int kk = 0; kk < 4; ++kk)
    afr[kk] = *reinterpret_cast<const short8*>(Arow + kk * 32 + lg * 8);
  f32x4 acc[16];
#pragma unroll
  for (int t = 0; t < 16; ++t) acc[t] = (f32x4){0.f, 0.f, 0.f, 0.f};
  const short8* Wp8 = reinterpret_cast<const short8*>(Wpk);
#pragma unroll
  for (int t = 0; t < 16; ++t) {
#pragma unroll
    for (int kk = 0; kk < 4; ++kk) {
      short8 bfr = Wp8[(kk * 4 + lg) * 256 + t * 16 + lr];
      acc[t] = __builtin_amdgcn_mfma_f32_16x16x32_bf16(afr[kk], bfr, acc[t], 0, 0, 0);
    }
  }
  float bias_l[16];
#pragma unroll
  for (int t = 0; t < 16; ++t) bias_l[t] = bf[t * 16 + lr];
  int rloc = r0 + lg * 4;
#pragma unroll
  for (int reg = 0; reg < 4; ++reg) {
    int row = rloc + reg;
    float v[16];
    float mT = -INFINITY, mS = -INFINITY, mA = -INFINITY;
#pragma unroll
    for (int t = 0; t < 16; ++t) {
      v[t] = acc[t][reg] + bias_l[t];
      int c = t * 16 + lr;
      if (c < 20) mT = fmaxf(mT, v[t]);
      else if (c < 50) mS = fmaxf(mS, v[t]);
      else if (c < 250) mA = fmaxf(mA, v[t]);
    }
#pragma unroll
    for (int o = 8; o; o >>= 1) {
      mT = fmaxf(mT, __shfl_xor(mT, o, 64));
      mS = fmaxf(mS, __shfl_xor(mS, o, 64));
      mA = fmaxf(mA, __shfl_xor(mA, o, 64));
    }
    float sT = 0.f, sS = 0.f, sA = 0.f;
#pragma unroll
    for (int t = 0; t < 16; ++t) {
      int c = t * 16 + lr;
      float m = (c < 20) ? mT : (c < 50) ? mS : mA;
      float ex = __expf(v[t] - m);
      v[t] = ex;
      if (c < 20) sT += ex;
      else if (c < 50) sS += ex;
      else if (c < 250) sA += ex;
    }
#pragma unroll
    for (int o = 8; o; o >>= 1) {
      sT += __shfl_xor(sT, o, 64);
      sS += __shfl_xor(sS, o, 64);
      sA += __shfl_xor(sA, o, 64);
    }
    float iT = 1.f / sT, iS = 1.f / sS, iA = 1.f / sA;
    if (row < n) {
#pragma unroll
      for (int t = 0; t < 16; ++t) {
        int c = t * 16 + lr;
        if (c < 20) outT[(size_t)row * 20 + c] = v[t] * iT;
        else if (c < 50) outS[(size_t)row * 30 + (c - 20)] = v[t] * iS;
        else if (c < 250) outA[(size_t)row * 200 + (c - 50)] = v[t] * iA;
      }
    }
  }
}

// ---- time head: softmax(x0 @ Wtf + btf) -----------------------------------
__global__ __launch_bounds__(256) void k_time(
    const float* __restrict__ x0, const float* __restrict__ Wtf,
    const float* __restrict__ btf, float* __restrict__ outT, int n) {
  __shared__ float sW[128][16];
  __shared__ float sb[16];
  for (int t = threadIdx.x; t < 128 * 16; t += 256) {
    int k = t >> 4, j = t & 15;
    sW[k][j] = (j < 15) ? Wtf[k * 15 + j] : 0.f;
  }
  if (threadIdx.x < 16) sb[threadIdx.x] = (threadIdx.x < 15) ? btf[threadIdx.x] : 0.f;
  __syncthreads();
  int j = threadIdx.x & 15;
  int rl = threadIdx.x >> 4;
  int r = blockIdx.x * 16 + rl;
  if (r >= n) return;
  float acc = sb[j];
  const float4* xr = reinterpret_cast<const float4*>(x0 + (size_t)r * 128);
  for (int k4 = 0; k4 < 32; ++k4) {
    float4 xv = xr[k4];
    acc += xv.x * sW[k4 * 4 + 0][j] + xv.y * sW[k4 * 4 + 1][j] +
           xv.z * sW[k4 * 4 + 2][j] + xv.w * sW[k4 * 4 + 3][j];
  }
  float m = (j < 15) ? acc : -INFINITY;
#pragma unroll
  for (int o = 8; o; o >>= 1) m = fmaxf(m, __shfl_xor(m, o, 16));
  float e = (j < 15) ? __expf(acc - m) : 0.f;
  float s = e;
#pragma unroll
  for (int o = 8; o; o >>= 1) s += __shfl_xor(s, o, 16);
  if (j < 15) outT[(size_t)r * 15 + j] = e / s;
}

// ---------------------------------------------------------------------------
extern "C" void kernel_launch(void* const* d_in, const int* in_sizes, int n_in,
                              void* d_out, int out_size, void* d_ws, size_t ws_size,
                              hipStream_t stream) {
  const float* x0 = (const float*)d_in[0];
  const int* ei = (const int*)d_in[1];
  const float* W1 = (const float*)d_in[2];
  const float* b1 = (const float*)d_in[3];
  const float* Wt = (const float*)d_in[4];
  const float* bt = (const float*)d_in[5];
  const float* Ws = (const float*)d_in[6];
  const float* bs = (const float*)d_in[7];
  const float* Wa = (const float*)d_in[8];
  const float* ba = (const float*)d_in[9];
  const float* Wct = (const float*)d_in[10];
  const float* bct = (const float*)d_in[11];
  const float* Wcs = (const float*)d_in[12];
  const float* bcs = (const float*)d_in[13];
  const float* Wtf = (const float*)d_in[14];
  const float* btf = (const float*)d_in[15];
  const float* Wca = (const float*)d_in[16];
  const float* bca = (const float*)d_in[17];
  (void)n_in; (void)out_size; (void)ws_size;

  int N = in_sizes[0] / 128;
  int E = in_sizes[1] / 2;
  float* out = (float*)d_out;

  char* ws = (char*)d_ws;
  size_t off = 0;
  auto alloc = [&](size_t bytes) -> void* {
    void* p = ws + off;
    off = (off + bytes + 255) & ~(size_t)255;
    return p;
  };
  int* deg = (int*)alloc((size_t)N * 4);
  int* row_off = (int*)alloc((size_t)N * 4);
  int* bsum = (int*)alloc(256 * 4);
  int* cursor = (int*)alloc((size_t)N * 4);
  float* dinv = (float*)alloc((size_t)N * 4);
  int* csr = (int*)alloc((size_t)E * 4);
  unsigned short* WfPk = (unsigned short*)alloc((size_t)128 * 256 * 2);
  unsigned short* W1Pk = (unsigned short*)alloc((size_t)128 * 128 * 2);
  float* bf = (float*)alloc(256 * 4);
  unsigned* Yb = (unsigned*)alloc((size_t)N * 64 * 4);  // bf16 table (pre-scaled x0)
  unsigned* Ab = (unsigned*)alloc((size_t)N * 64 * 4);  // bf16 table (agg results)
  unsigned* Bb = (unsigned*)alloc((size_t)N * 64 * 4);  // bf16 table (hidden)

  const int* srcp = ei;
  const int* dstp = ei + E;
  int gE = (E + 255) / 256;
  int gN = (N + 255) / 256;  // 196 <= 256, required by k_scan2

  k_zero<<<gN, 256, 0, stream>>>(deg, N);
  k_deg<<<gE, 256, 0, stream>>>(dstp, E, deg);
  k_scan1<<<gN, 256, 0, stream>>>(deg, N, row_off, bsum);
  k_scan2<<<1, 256, 0, stream>>>(bsum, gN);
  k_finalize<<<gN, 256, 0, stream>>>(row_off, bsum, deg, cursor, dinv, N);
  k_fill<<<gE, 256, 0, stream>>>(srcp, dstp, E, cursor, csr);
  // weight packing (independent of graph work)
  k_pack128<<<64, 256, 0, stream>>>(W1, W1Pk);
  k_fuse<<<256, 128, 0, stream>>>(Wt, bt, Wct, bct, Ws, bs, Wcs, bcs, Wa, ba, Wca,
                                  bca, WfPk, bf);
  // Yb = bf16(dinv*x0) ; Ab = agg(Yb)
  k_scale<<<(N * 64 + 255) / 256, 256, 0, stream>>>(x0, dinv, Yb, N);
  k_agg<<<(N + 3) / 4, 256, 0, stream>>>(Yb, Ab, row_off, deg, csr, dinv, N);
  // Bb = bf16(dinv*relu(Ab@W1+b1))   [MFMA, no LDS]
  k_mfma_gemm128<<<(N + 63) / 64, 256, 0, stream>>>(
      (const short*)Ab, W1Pk, b1, dinv, (unsigned short*)Bb, N);
  // Ab = agg(Bb)
  k_agg<<<(N + 3) / 4, 256, 0, stream>>>(Bb, Ab, row_off, deg, csr, dinv, N);
  // heads: MFMA + fused segmented softmax  [no LDS]
  k_heads_fused<<<(N + 63) / 64, 256, 0, stream>>>(
      (const short*)Ab, WfPk, bf, out, out + (size_t)N * 20, out + (size_t)N * 65, N);
  k_time<<<(N + 15) / 16, 256, 0, stream>>>(x0, Wtf, btf, out + (size_t)N * 50, N);
}

// Round 7
// 351.738 us; speedup vs baseline: 1.9547x; 1.0850x over previous
//
#include <hip/hip_runtime.h>
#include <math.h>

// ---------------------------------------------------------------------------
// GCN forward. R6: MFMA kernels split output cols across 2 waves (wave =
// row-group x col-half): halves per-wave B-load/MFMA/epilogue serial work and
// doubles wave supply (grid 2x). A re-staged via small LDS (proven better in
// R4). Author-head max/sum exchanged across col-half waves via tiny LDS.
// ---------------------------------------------------------------------------

typedef short short8 __attribute__((ext_vector_type(8)));
typedef float f32x4 __attribute__((ext_vector_type(4)));

static __device__ __forceinline__ unsigned short f2bf(float x) {  // RNE
  unsigned u = __float_as_uint(x);
  u += 0x7fff + ((u >> 16) & 1);
  return (unsigned short)(u >> 16);
}
static __device__ __forceinline__ unsigned pack2bf(float lo, float hi) {
  return ((unsigned)f2bf(hi) << 16) | (unsigned)f2bf(lo);
}
static __device__ __forceinline__ float bflo(unsigned u) {
  return __uint_as_float(u << 16);
}
static __device__ __forceinline__ float bfhi(unsigned u) {
  return __uint_as_float(u & 0xffff0000u);
}

// ---- zero int buffer ------------------------------------------------------
__global__ void k_zero(int* __restrict__ p, int n) {
  int i = blockIdx.x * blockDim.x + threadIdx.x;
  if (i < n) p[i] = 0;
}

// ---- degree count (in-degree over dst) ------------------------------------
__global__ void k_deg(const int* __restrict__ dst, int E, int* __restrict__ deg) {
  int e = blockIdx.x * blockDim.x + threadIdx.x;
  if (e < E) atomicAdd(&deg[dst[e]], 1);
}

// ---- 3-kernel exclusive scan over N ints ----------------------------------
__global__ void k_scan1(const int* __restrict__ deg, int n,
                        int* __restrict__ excl, int* __restrict__ bsum) {
  __shared__ int sm[256];
  int i = blockIdx.x * 256 + threadIdx.x;
  int v = (i < n) ? deg[i] : 0;
  sm[threadIdx.x] = v;
  __syncthreads();
#pragma unroll
  for (int o = 1; o < 256; o <<= 1) {
    int t = (threadIdx.x >= o) ? sm[threadIdx.x - o] : 0;
    __syncthreads();
    sm[threadIdx.x] += t;
    __syncthreads();
  }
  if (i < n) excl[i] = sm[threadIdx.x] - v;
  if (threadIdx.x == 255) bsum[blockIdx.x] = sm[255];
}

__global__ void k_scan2(int* __restrict__ bsum, int nb) {
  __shared__ int sm[256];
  int v = (threadIdx.x < nb) ? bsum[threadIdx.x] : 0;
  sm[threadIdx.x] = v;
  __syncthreads();
#pragma unroll
  for (int o = 1; o < 256; o <<= 1) {
    int t = (threadIdx.x >= o) ? sm[threadIdx.x - o] : 0;
    __syncthreads();
    sm[threadIdx.x] += t;
    __syncthreads();
  }
  if (threadIdx.x < nb) bsum[threadIdx.x] = sm[threadIdx.x] - v;  // exclusive
}

__global__ void k_finalize(int* __restrict__ row_off, const int* __restrict__ bsum,
                           const int* __restrict__ deg, int* __restrict__ cursor,
                           float* __restrict__ dinv, int n) {
  int i = blockIdx.x * 256 + threadIdx.x;
  if (i < n) {
    int ro = row_off[i] + bsum[blockIdx.x];
    row_off[i] = ro;
    cursor[i] = ro;
    dinv[i] = rsqrtf((float)(deg[i] + 1));  // +1 self-loop
  }
}

// ---- CSR fill -------------------------------------------------------------
__global__ void k_fill(const int* __restrict__ src, const int* __restrict__ dst,
                       int E, int* __restrict__ cursor, int* __restrict__ csr) {
  int e = blockIdx.x * blockDim.x + threadIdx.x;
  if (e < E) {
    int d = dst[e];
    int p = atomicAdd(&cursor[d], 1);
    csr[p] = src[e];
  }
}

// ---- row pre-scale -> bf16: Y[i][:] = bf16(dinv[i] * X[i][:]) -------------
__global__ __launch_bounds__(256) void k_scale(
    const float* __restrict__ X, const float* __restrict__ dinv,
    unsigned* __restrict__ Y, int n) {
  int t = blockIdx.x * 256 + threadIdx.x;  // one uint (2 cols) per thread
  int total = n * 64;
  if (t < total) {
    int row = t >> 6;
    float d = dinv[row];
    float2 v = reinterpret_cast<const float2*>(X)[t];
    Y[t] = pack2bf(v.x * d, v.y * d);
  }
}

// ---- aggregation on bf16 tables: out[i] = bf16(dinv[i]*(sum_s Y[s] + Y[i]))
__global__ __launch_bounds__(256) void k_agg(
    const unsigned* __restrict__ Y, unsigned* __restrict__ out,
    const int* __restrict__ row_off, const int* __restrict__ deg,
    const int* __restrict__ csr, const float* __restrict__ dinv, int n) {
  int wave = threadIdx.x >> 6;
  int lane = threadIdx.x & 63;
  int i = blockIdx.x * 4 + wave;
  if (i >= n) return;
  int start = row_off[i];
  int cnt = deg[i];
  float ax = 0.f, ay = 0.f;
  int j = 0;
  for (; j + 3 < cnt; j += 4) {
    int s0 = csr[start + j];
    int s1 = csr[start + j + 1];
    int s2 = csr[start + j + 2];
    int s3 = csr[start + j + 3];
    unsigned u0 = Y[(size_t)s0 * 64 + lane];
    unsigned u1 = Y[(size_t)s1 * 64 + lane];
    unsigned u2 = Y[(size_t)s2 * 64 + lane];
    unsigned u3 = Y[(size_t)s3 * 64 + lane];
    ax += (bflo(u0) + bflo(u1)) + (bflo(u2) + bflo(u3));
    ay += (bfhi(u0) + bfhi(u1)) + (bfhi(u2) + bfhi(u3));
  }
  for (; j < cnt; ++j) {
    int s0 = csr[start + j];
    unsigned u0 = Y[(size_t)s0 * 64 + lane];
    ax += bflo(u0);
    ay += bfhi(u0);
  }
  unsigned us = Y[(size_t)i * 64 + lane];
  float di = dinv[i];
  out[(size_t)i * 64 + lane] = pack2bf((ax + bflo(us)) * di, (ay + bfhi(us)) * di);
}

// ---- pack W1 [128][128] fp32 -> bf16 fragment layout [(k>>3)][col][k&7] ---
__global__ void k_pack128(const float* __restrict__ W, unsigned short* __restrict__ P) {
  int t = blockIdx.x * 256 + threadIdx.x;  // 16384
  int i = t >> 7, c = t & 127;
  P[((i >> 3) * 128 + c) * 8 + (i & 7)] = f2bf(W[t]);
}

// ---- fuse head weights into bf16 packed Wf --------------------------------
__global__ void k_fuse(const float* __restrict__ Wt, const float* __restrict__ bt,
                       const float* __restrict__ Wct, const float* __restrict__ bct,
                       const float* __restrict__ Ws, const float* __restrict__ bs,
                       const float* __restrict__ Wcs, const float* __restrict__ bcs,
                       const float* __restrict__ Wa, const float* __restrict__ ba,
                       const float* __restrict__ Wca, const float* __restrict__ bca,
                       unsigned short* __restrict__ WfPk, float* __restrict__ bf) {
  int c = blockIdx.x;   // 0..255
  int i = threadIdx.x;  // 0..127
  float acc = 0.f, bacc = 0.f;
  if (c < 20) {
    for (int k = 0; k < 20; ++k) {
      float w2 = Wct[k * 20 + c];
      acc += Wt[i * 20 + k] * w2;
      bacc += bt[k] * w2;
    }
    bacc += bct[c];
  } else if (c < 50) {
    int cc = c - 20;
    for (int k = 0; k < 30; ++k) {
      float w2 = Wcs[k * 30 + cc];
      acc += Ws[i * 30 + k] * w2;
      bacc += bs[k] * w2;
    }
    bacc += bcs[cc];
  } else if (c < 250) {
    int cc = c - 50;
    for (int k = 0; k < 200; ++k) {
      float w2 = Wca[k * 200 + cc];
      acc += Wa[i * 200 + k] * w2;
      bacc += ba[k] * w2;
    }
    bacc += bca[cc];
  }
  WfPk[((i >> 3) * 256 + c) * 8 + (i & 7)] = f2bf(acc);
  if (i == 0) bf[c] = bacc;
}

// ---- stage 32 bf16 rows into LDS ------------------------------------------
static __device__ __forceinline__ void stage32(
    const short* __restrict__ A, short (*sAb)[136], int rowBase, int n, int tid) {
  for (int t = tid; t < 32 * 16; t += 256) {
    int r = t >> 4, c8 = t & 15;
    int gr = rowBase + r;
    short8 v = (short8){0, 0, 0, 0, 0, 0, 0, 0};
    if (gr < n) v = *reinterpret_cast<const short8*>(A + (size_t)gr * 128 + c8 * 8);
    *reinterpret_cast<short8*>(&sAb[r][c8 * 8]) = v;
  }
}

// ---- MFMA GEMM 128x128, col-split: wave=(rowgrp, colhalf); 16 rows x 64 cols
__global__ __launch_bounds__(256) void k_mfma_gemm128(
    const short* __restrict__ A, const unsigned short* __restrict__ Wpk,
    const float* __restrict__ bias, const float* __restrict__ dinv,
    unsigned short* __restrict__ out, int n) {
  __shared__ short sAb[32][136];
  int rowBase = blockIdx.x * 32;
  stage32(A, sAb, rowBase, n, threadIdx.x);
  __syncthreads();
  int wave = threadIdx.x >> 6, lane = threadIdx.x & 63;
  int rg = wave >> 1, ch = wave & 1;
  int lr = lane & 15, lg = lane >> 4;
  int r0 = rowBase + rg * 16;
  short8 afr[4];
#pragma unroll
  for (int kk = 0; kk < 4; ++kk)
    afr[kk] = *reinterpret_cast<const short8*>(&sAb[rg * 16 + lr][kk * 32 + lg * 8]);
  f32x4 acc[4];
#pragma unroll
  for (int t = 0; t < 4; ++t) acc[t] = (f32x4){0.f, 0.f, 0.f, 0.f};
  const short8* Wp8 = reinterpret_cast<const short8*>(Wpk);
#pragma unroll
  for (int t = 0; t < 4; ++t) {
#pragma unroll
    for (int kk = 0; kk < 4; ++kk) {
      short8 bfr = Wp8[(kk * 4 + lg) * 128 + ch * 64 + t * 16 + lr];
      acc[t] = __builtin_amdgcn_mfma_f32_16x16x32_bf16(afr[kk], bfr, acc[t], 0, 0, 0);
    }
  }
  int rloc = r0 + lg * 4;
#pragma unroll
  for (int t = 0; t < 4; ++t) {
    int col = ch * 64 + t * 16 + lr;
    float b = bias[col];
#pragma unroll
    for (int reg = 0; reg < 4; ++reg) {
      int row = rloc + reg;
      if (row < n) {
        float v = fmaxf(acc[t][reg] + b, 0.f) * dinv[row];
        out[(size_t)row * 128 + col] = f2bf(v);
      }
    }
  }
}

// ---- heads: MFMA 128x256 col-split + fused segmented softmax --------------
// wave=(rowgrp rg, colhalf ch): 16 rows x 128 cols. Author head spans both
// halves -> exchange per-row max/sum via LDS (2 barriers).
__global__ __launch_bounds__(256) void k_heads_fused(
    const short* __restrict__ A, const unsigned short* __restrict__ Wpk,
    const float* __restrict__ bf, float* __restrict__ outT,
    float* __restrict__ outS, float* __restrict__ outA, int n) {
  __shared__ short sAb[32][136];
  __shared__ float aM[2][2][16];  // [rg][ch][row-in-group] author partial max
  __shared__ float aS[2][2][16];  // author partial sum
  int rowBase = blockIdx.x * 32;
  stage32(A, sAb, rowBase, n, threadIdx.x);
  __syncthreads();
  int wave = threadIdx.x >> 6, lane = threadIdx.x & 63;
  int rg = wave >> 1, ch = wave & 1;
  int lr = lane & 15, lg = lane >> 4;
  int r0 = rowBase + rg * 16;
  int cb = ch * 128;
  short8 afr[4];
#pragma unroll
  for (int kk = 0; kk < 4; ++kk)
    afr[kk] = *reinterpret_cast<const short8*>(&sAb[rg * 16 + lr][kk * 32 + lg * 8]);
  f32x4 acc[8];
#pragma unroll
  for (int t = 0; t < 8; ++t) acc[t] = (f32x4){0.f, 0.f, 0.f, 0.f};
  const short8* Wp8 = reinterpret_cast<const short8*>(Wpk);
#pragma unroll
  for (int t = 0; t < 8; ++t) {
#pragma unroll
    for (int kk = 0; kk < 4; ++kk) {
      short8 bfr = Wp8[(kk * 4 + lg) * 256 + cb + t * 16 + lr];
      acc[t] = __builtin_amdgcn_mfma_f32_16x16x32_bf16(afr[kk], bfr, acc[t], 0, 0, 0);
    }
  }
  float bias_l[8];
#pragma unroll
  for (int t = 0; t < 8; ++t) bias_l[t] = bf[cb + t * 16 + lr];
  // phase 1: v = acc + bias ; per-row partial maxes
  float mTr[4], mSr[4], mAr[4];
#pragma unroll
  for (int reg = 0; reg < 4; ++reg) {
    float mT = -INFINITY, mS = -INFINITY, mA = -INFINITY;
#pragma unroll
    for (int t = 0; t < 8; ++t) {
      int c = cb + t * 16 + lr;
      float val = acc[t][reg] + bias_l[t];
      acc[t][reg] = val;
      if (c < 20) mT = fmaxf(mT, val);
      else if (c < 50) mS = fmaxf(mS, val);
      else if (c < 250) mA = fmaxf(mA, val);
    }
#pragma unroll
    for (int o = 8; o; o >>= 1) {
      mT = fmaxf(mT, __shfl_xor(mT, o, 64));
      mS = fmaxf(mS, __shfl_xor(mS, o, 64));
      mA = fmaxf(mA, __shfl_xor(mA, o, 64));
    }
    mTr[reg] = mT; mSr[reg] = mS; mAr[reg] = mA;
    if (lr == 0) aM[rg][ch][lg * 4 + reg] = mA;
  }
  __syncthreads();
#pragma unroll
  for (int reg = 0; reg < 4; ++reg)
    mAr[reg] = fmaxf(mAr[reg], aM[rg][ch ^ 1][lg * 4 + reg]);
  // phase 2: exp ; per-row partial sums
  float sTr[4], sSr[4], sAr[4];
#pragma unroll
  for (int reg = 0; reg < 4; ++reg) {
    float sT = 0.f, sS = 0.f, sA = 0.f;
#pragma unroll
    for (int t = 0; t < 8; ++t) {
      int c = cb + t * 16 + lr;
      float m = (c < 20) ? mTr[reg] : (c < 50) ? mSr[reg] : mAr[reg];
      float e = __expf(acc[t][reg] - m);
      acc[t][reg] = e;
      if (c < 20) sT += e;
      else if (c < 50) sS += e;
      else if (c < 250) sA += e;
    }
#pragma unroll
    for (int o = 8; o; o >>= 1) {
      sT += __shfl_xor(sT, o, 64);
      sS += __shfl_xor(sS, o, 64);
      sA += __shfl_xor(sA, o, 64);
    }
    sTr[reg] = sT; sSr[reg] = sS; sAr[reg] = sA;
    if (lr == 0) aS[rg][ch][lg * 4 + reg] = sA;
  }
  __syncthreads();
#pragma unroll
  for (int reg = 0; reg < 4; ++reg)
    sAr[reg] += aS[rg][ch ^ 1][lg * 4 + reg];
  // phase 3: normalize + scatter stores
  int rloc = r0 + lg * 4;
#pragma unroll
  for (int reg = 0; reg < 4; ++reg) {
    int row = rloc + reg;
    if (row >= n) continue;
    float iT = 1.f / sTr[reg], iS = 1.f / sSr[reg], iA = 1.f / sAr[reg];
#pragma unroll
    for (int t = 0; t < 8; ++t) {
      int c = cb + t * 16 + lr;
      float e = acc[t][reg];
      if (c < 20) outT[(size_t)row * 20 + c] = e * iT;
      else if (c < 50) outS[(size_t)row * 30 + (c - 20)] = e * iS;
      else if (c < 250) outA[(size_t)row * 200 + (c - 50)] = e * iA;
    }
  }
}

// ---- time head: softmax(x0 @ Wtf + btf) -----------------------------------
__global__ __launch_bounds__(256) void k_time(
    const float* __restrict__ x0, const float* __restrict__ Wtf,
    const float* __restrict__ btf, float* __restrict__ outT, int n) {
  __shared__ float sW[128][16];
  __shared__ float sb[16];
  for (int t = threadIdx.x; t < 128 * 16; t += 256) {
    int k = t >> 4, j = t & 15;
    sW[k][j] = (j < 15) ? Wtf[k * 15 + j] : 0.f;
  }
  if (threadIdx.x < 16) sb[threadIdx.x] = (threadIdx.x < 15) ? btf[threadIdx.x] : 0.f;
  __syncthreads();
  int j = threadIdx.x & 15;
  int rl = threadIdx.x >> 4;
  int r = blockIdx.x * 16 + rl;
  if (r >= n) return;
  float acc = sb[j];
  const float4* xr = reinterpret_cast<const float4*>(x0 + (size_t)r * 128);
  for (int k4 = 0; k4 < 32; ++k4) {
    float4 xv = xr[k4];
    acc += xv.x * sW[k4 * 4 + 0][j] + xv.y * sW[k4 * 4 + 1][j] +
           xv.z * sW[k4 * 4 + 2][j] + xv.w * sW[k4 * 4 + 3][j];
  }
  float m = (j < 15) ? acc : -INFINITY;
#pragma unroll
  for (int o = 8; o; o >>= 1) m = fmaxf(m, __shfl_xor(m, o, 16));
  float e = (j < 15) ? __expf(acc - m) : 0.f;
  float s = e;
#pragma unroll
  for (int o = 8; o; o >>= 1) s += __shfl_xor(s, o, 16);
  if (j < 15) outT[(size_t)r * 15 + j] = e / s;
}

// ---------------------------------------------------------------------------
extern "C" void kernel_launch(void* const* d_in, const int* in_sizes, int n_in,
                              void* d_out, int out_size, void* d_ws, size_t ws_size,
                              hipStream_t stream) {
  const float* x0 = (const float*)d_in[0];
  const int* ei = (const int*)d_in[1];
  const float* W1 = (const float*)d_in[2];
  const float* b1 = (const float*)d_in[3];
  const float* Wt = (const float*)d_in[4];
  const float* bt = (const float*)d_in[5];
  const float* Ws = (const float*)d_in[6];
  const float* bs = (const float*)d_in[7];
  const float* Wa = (const float*)d_in[8];
  const float* ba = (const float*)d_in[9];
  const float* Wct = (const float*)d_in[10];
  const float* bct = (const float*)d_in[11];
  const float* Wcs = (const float*)d_in[12];
  const float* bcs = (const float*)d_in[13];
  const float* Wtf = (const float*)d_in[14];
  const float* btf = (const float*)d_in[15];
  const float* Wca = (const float*)d_in[16];
  const float* bca = (const float*)d_in[17];
  (void)n_in; (void)out_size; (void)ws_size;

  int N = in_sizes[0] / 128;
  int E = in_sizes[1] / 2;
  float* out = (float*)d_out;

  char* ws = (char*)d_ws;
  size_t off = 0;
  auto alloc = [&](size_t bytes) -> void* {
    void* p = ws + off;
    off = (off + bytes + 255) & ~(size_t)255;
    return p;
  };
  int* deg = (int*)alloc((size_t)N * 4);
  int* row_off = (int*)alloc((size_t)N * 4);
  int* bsum = (int*)alloc(256 * 4);
  int* cursor = (int*)alloc((size_t)N * 4);
  float* dinv = (float*)alloc((size_t)N * 4);
  int* csr = (int*)alloc((size_t)E * 4);
  unsigned short* WfPk = (unsigned short*)alloc((size_t)128 * 256 * 2);
  unsigned short* W1Pk = (unsigned short*)alloc((size_t)128 * 128 * 2);
  float* bf = (float*)alloc(256 * 4);
  unsigned* Yb = (unsigned*)alloc((size_t)N * 64 * 4);  // bf16 table (pre-scaled x0)
  unsigned* Ab = (unsigned*)alloc((size_t)N * 64 * 4);  // bf16 table (agg results)
  unsigned* Bb = (unsigned*)alloc((size_t)N * 64 * 4);  // bf16 table (hidden)

  const int* srcp = ei;
  const int* dstp = ei + E;
  int gE = (E + 255) / 256;
  int gN = (N + 255) / 256;  // 196 <= 256, required by k_scan2
  int g32 = (N + 31) / 32;

  k_zero<<<gN, 256, 0, stream>>>(deg, N);
  k_deg<<<gE, 256, 0, stream>>>(dstp, E, deg);
  k_scan1<<<gN, 256, 0, stream>>>(deg, N, row_off, bsum);
  k_scan2<<<1, 256, 0, stream>>>(bsum, gN);
  k_finalize<<<gN, 256, 0, stream>>>(row_off, bsum, deg, cursor, dinv, N);
  k_fill<<<gE, 256, 0, stream>>>(srcp, dstp, E, cursor, csr);
  // weight packing (independent of graph work)
  k_pack128<<<64, 256, 0, stream>>>(W1, W1Pk);
  k_fuse<<<256, 128, 0, stream>>>(Wt, bt, Wct, bct, Ws, bs, Wcs, bcs, Wa, ba, Wca,
                                  bca, WfPk, bf);
  // Yb = bf16(dinv*x0) ; Ab = agg(Yb)
  k_scale<<<(N * 64 + 255) / 256, 256, 0, stream>>>(x0, dinv, Yb, N);
  k_agg<<<(N + 3) / 4, 256, 0, stream>>>(Yb, Ab, row_off, deg, csr, dinv, N);
  // Bb = bf16(dinv*relu(Ab@W1+b1))   [MFMA, col-split]
  k_mfma_gemm128<<<g32, 256, 0, stream>>>(
      (const short*)Ab, W1Pk, b1, dinv, (unsigned short*)Bb, N);
  // Ab = agg(Bb)
  k_agg<<<(N + 3) / 4, 256, 0, stream>>>(Bb, Ab, row_off, deg, csr, dinv, N);
  // heads: MFMA + fused segmented softmax  [col-split]
  k_heads_fused<<<g32, 256, 0, stream>>>(
      (const short*)Ab, WfPk, bf, out, out + (size_t)N * 20, out + (size_t)N * 65, N);
  k_time<<<(N + 15) / 16, 256, 0, stream>>>(x0, Wtf, btf, out + (size_t)N * 50, N);
}

// Round 8
// 340.188 us; speedup vs baseline: 2.0210x; 1.0340x over previous
//
#include <hip/hip_runtime.h>
#include <math.h>

// ---------------------------------------------------------------------------
// GCN forward. R7: uint16 CSR (halves scatter write-amplification in k_fill),
// hipMemsetAsync replaces k_zero, k_agg widened to uint2/lane (2 nodes/wave).
// Pipeline: bf16 tables, col-split MFMA GEMMs, fused segmented softmax.
// ---------------------------------------------------------------------------

typedef short short8 __attribute__((ext_vector_type(8)));
typedef float f32x4 __attribute__((ext_vector_type(4)));

static __device__ __forceinline__ unsigned short f2bf(float x) {  // RNE
  unsigned u = __float_as_uint(x);
  u += 0x7fff + ((u >> 16) & 1);
  return (unsigned short)(u >> 16);
}
static __device__ __forceinline__ unsigned pack2bf(float lo, float hi) {
  return ((unsigned)f2bf(hi) << 16) | (unsigned)f2bf(lo);
}
static __device__ __forceinline__ float bflo(unsigned u) {
  return __uint_as_float(u << 16);
}
static __device__ __forceinline__ float bfhi(unsigned u) {
  return __uint_as_float(u & 0xffff0000u);
}

// ---- degree count (in-degree over dst) ------------------------------------
__global__ void k_deg(const int* __restrict__ dst, int E, int* __restrict__ deg) {
  int e = blockIdx.x * blockDim.x + threadIdx.x;
  if (e < E) atomicAdd(&deg[dst[e]], 1);
}

// ---- 3-kernel exclusive scan over N ints ----------------------------------
__global__ void k_scan1(const int* __restrict__ deg, int n,
                        int* __restrict__ excl, int* __restrict__ bsum) {
  __shared__ int sm[256];
  int i = blockIdx.x * 256 + threadIdx.x;
  int v = (i < n) ? deg[i] : 0;
  sm[threadIdx.x] = v;
  __syncthreads();
#pragma unroll
  for (int o = 1; o < 256; o <<= 1) {
    int t = (threadIdx.x >= o) ? sm[threadIdx.x - o] : 0;
    __syncthreads();
    sm[threadIdx.x] += t;
    __syncthreads();
  }
  if (i < n) excl[i] = sm[threadIdx.x] - v;
  if (threadIdx.x == 255) bsum[blockIdx.x] = sm[255];
}

__global__ void k_scan2(int* __restrict__ bsum, int nb) {
  __shared__ int sm[256];
  int v = (threadIdx.x < nb) ? bsum[threadIdx.x] : 0;
  sm[threadIdx.x] = v;
  __syncthreads();
#pragma unroll
  for (int o = 1; o < 256; o <<= 1) {
    int t = (threadIdx.x >= o) ? sm[threadIdx.x - o] : 0;
    __syncthreads();
    sm[threadIdx.x] += t;
    __syncthreads();
  }
  if (threadIdx.x < nb) bsum[threadIdx.x] = sm[threadIdx.x] - v;  // exclusive
}

__global__ void k_finalize(int* __restrict__ row_off, const int* __restrict__ bsum,
                           const int* __restrict__ deg, int* __restrict__ cursor,
                           float* __restrict__ dinv, int n) {
  int i = blockIdx.x * 256 + threadIdx.x;
  if (i < n) {
    int ro = row_off[i] + bsum[blockIdx.x];
    row_off[i] = ro;
    cursor[i] = ro;
    dinv[i] = rsqrtf((float)(deg[i] + 1));  // +1 self-loop
  }
}

// ---- CSR fill (uint16 indices; N < 65536) ---------------------------------
__global__ void k_fill(const int* __restrict__ src, const int* __restrict__ dst,
                       int E, int* __restrict__ cursor,
                       unsigned short* __restrict__ csr) {
  int e = blockIdx.x * blockDim.x + threadIdx.x;
  if (e < E) {
    int d = dst[e];
    int p = atomicAdd(&cursor[d], 1);
    csr[p] = (unsigned short)src[e];
  }
}

// ---- row pre-scale -> bf16: Y[i][:] = bf16(dinv[i] * X[i][:]) -------------
__global__ __launch_bounds__(256) void k_scale(
    const float* __restrict__ X, const float* __restrict__ dinv,
    unsigned* __restrict__ Y, int n) {
  int t = blockIdx.x * 256 + threadIdx.x;  // one uint (2 cols) per thread
  int total = n * 64;
  if (t < total) {
    int row = t >> 6;
    float d = dinv[row];
    float2 v = reinterpret_cast<const float2*>(X)[t];
    Y[t] = pack2bf(v.x * d, v.y * d);
  }
}

// ---- aggregation on bf16 tables: out[i] = bf16(dinv[i]*(sum_s Y[s] + Y[i]))
// 2 nodes/wave: 32 lanes per node, uint2 (4 bf16 cols) per lane; fp32 accum.
__global__ __launch_bounds__(256) void k_agg(
    const unsigned* __restrict__ Y, unsigned* __restrict__ out,
    const int* __restrict__ row_off, const int* __restrict__ deg,
    const unsigned short* __restrict__ csr, const float* __restrict__ dinv,
    int n) {
  int wave = threadIdx.x >> 6;
  int lane = threadIdx.x & 63;
  int sub = lane >> 5;   // node within wave
  int sl = lane & 31;    // lane within node (uint2 index)
  int i = blockIdx.x * 8 + wave * 2 + sub;
  if (i >= n) return;
  int start = row_off[i];
  int cnt = deg[i];
  const uint2* Yv = reinterpret_cast<const uint2*>(Y);
  float a0 = 0.f, a1 = 0.f, a2 = 0.f, a3 = 0.f;
  int j = 0;
  for (; j + 3 < cnt; j += 4) {
    int s0 = csr[start + j];
    int s1 = csr[start + j + 1];
    int s2 = csr[start + j + 2];
    int s3 = csr[start + j + 3];
    uint2 u0 = Yv[(size_t)s0 * 32 + sl];
    uint2 u1 = Yv[(size_t)s1 * 32 + sl];
    uint2 u2 = Yv[(size_t)s2 * 32 + sl];
    uint2 u3 = Yv[(size_t)s3 * 32 + sl];
    a0 += (bflo(u0.x) + bflo(u1.x)) + (bflo(u2.x) + bflo(u3.x));
    a1 += (bfhi(u0.x) + bfhi(u1.x)) + (bfhi(u2.x) + bfhi(u3.x));
    a2 += (bflo(u0.y) + bflo(u1.y)) + (bflo(u2.y) + bflo(u3.y));
    a3 += (bfhi(u0.y) + bfhi(u1.y)) + (bfhi(u2.y) + bfhi(u3.y));
  }
  for (; j < cnt; ++j) {
    int s0 = csr[start + j];
    uint2 u0 = Yv[(size_t)s0 * 32 + sl];
    a0 += bflo(u0.x);
    a1 += bfhi(u0.x);
    a2 += bflo(u0.y);
    a3 += bfhi(u0.y);
  }
  uint2 us = Yv[(size_t)i * 32 + sl];
  float di = dinv[i];
  uint2 r;
  r.x = pack2bf((a0 + bflo(us.x)) * di, (a1 + bfhi(us.x)) * di);
  r.y = pack2bf((a2 + bflo(us.y)) * di, (a3 + bfhi(us.y)) * di);
  reinterpret_cast<uint2*>(out)[(size_t)i * 32 + sl] = r;
}

// ---- pack W1 [128][128] fp32 -> bf16 fragment layout [(k>>3)][col][k&7] ---
__global__ void k_pack128(const float* __restrict__ W, unsigned short* __restrict__ P) {
  int t = blockIdx.x * 256 + threadIdx.x;  // 16384
  int i = t >> 7, c = t & 127;
  P[((i >> 3) * 128 + c) * 8 + (i & 7)] = f2bf(W[t]);
}

// ---- fuse head weights into bf16 packed Wf --------------------------------
__global__ void k_fuse(const float* __restrict__ Wt, const float* __restrict__ bt,
                       const float* __restrict__ Wct, const float* __restrict__ bct,
                       const float* __restrict__ Ws, const float* __restrict__ bs,
                       const float* __restrict__ Wcs, const float* __restrict__ bcs,
                       const float* __restrict__ Wa, const float* __restrict__ ba,
                       const float* __restrict__ Wca, const float* __restrict__ bca,
                       unsigned short* __restrict__ WfPk, float* __restrict__ bf) {
  int c = blockIdx.x;   // 0..255
  int i = threadIdx.x;  // 0..127
  float acc = 0.f, bacc = 0.f;
  if (c < 20) {
    for (int k = 0; k < 20; ++k) {
      float w2 = Wct[k * 20 + c];
      acc += Wt[i * 20 + k] * w2;
      bacc += bt[k] * w2;
    }
    bacc += bct[c];
  } else if (c < 50) {
    int cc = c - 20;
    for (int k = 0; k < 30; ++k) {
      float w2 = Wcs[k * 30 + cc];
      acc += Ws[i * 30 + k] * w2;
      bacc += bs[k] * w2;
    }
    bacc += bcs[cc];
  } else if (c < 250) {
    int cc = c - 50;
    for (int k = 0; k < 200; ++k) {
      float w2 = Wca[k * 200 + cc];
      acc += Wa[i * 200 + k] * w2;
      bacc += ba[k] * w2;
    }
    bacc += bca[cc];
  }
  WfPk[((i >> 3) * 256 + c) * 8 + (i & 7)] = f2bf(acc);
  if (i == 0) bf[c] = bacc;
}

// ---- stage 32 bf16 rows into LDS ------------------------------------------
static __device__ __forceinline__ void stage32(
    const short* __restrict__ A, short (*sAb)[136], int rowBase, int n, int tid) {
  for (int t = tid; t < 32 * 16; t += 256) {
    int r = t >> 4, c8 = t & 15;
    int gr = rowBase + r;
    short8 v = (short8){0, 0, 0, 0, 0, 0, 0, 0};
    if (gr < n) v = *reinterpret_cast<const short8*>(A + (size_t)gr * 128 + c8 * 8);
    *reinterpret_cast<short8*>(&sAb[r][c8 * 8]) = v;
  }
}

// ---- MFMA GEMM 128x128, col-split: wave=(rowgrp, colhalf); 16 rows x 64 cols
__global__ __launch_bounds__(256) void k_mfma_gemm128(
    const short* __restrict__ A, const unsigned short* __restrict__ Wpk,
    const float* __restrict__ bias, const float* __restrict__ dinv,
    unsigned short* __restrict__ out, int n) {
  __shared__ short sAb[32][136];
  int rowBase = blockIdx.x * 32;
  stage32(A, sAb, rowBase, n, threadIdx.x);
  __syncthreads();
  int wave = threadIdx.x >> 6, lane = threadIdx.x & 63;
  int rg = wave >> 1, ch = wave & 1;
  int lr = lane & 15, lg = lane >> 4;
  int r0 = rowBase + rg * 16;
  short8 afr[4];
#pragma unroll
  for (int kk = 0; kk < 4; ++kk)
    afr[kk] = *reinterpret_cast<const short8*>(&sAb[rg * 16 + lr][kk * 32 + lg * 8]);
  f32x4 acc[4];
#pragma unroll
  for (int t = 0; t < 4; ++t) acc[t] = (f32x4){0.f, 0.f, 0.f, 0.f};
  const short8* Wp8 = reinterpret_cast<const short8*>(Wpk);
#pragma unroll
  for (int t = 0; t < 4; ++t) {
#pragma unroll
    for (int kk = 0; kk < 4; ++kk) {
      short8 bfr = Wp8[(kk * 4 + lg) * 128 + ch * 64 + t * 16 + lr];
      acc[t] = __builtin_amdgcn_mfma_f32_16x16x32_bf16(afr[kk], bfr, acc[t], 0, 0, 0);
    }
  }
  int rloc = r0 + lg * 4;
#pragma unroll
  for (int t = 0; t < 4; ++t) {
    int col = ch * 64 + t * 16 + lr;
    float b = bias[col];
#pragma unroll
    for (int reg = 0; reg < 4; ++reg) {
      int row = rloc + reg;
      if (row < n) {
        float v = fmaxf(acc[t][reg] + b, 0.f) * dinv[row];
        out[(size_t)row * 128 + col] = f2bf(v);
      }
    }
  }
}

// ---- heads: MFMA 128x256 col-split + fused segmented softmax --------------
__global__ __launch_bounds__(256) void k_heads_fused(
    const short* __restrict__ A, const unsigned short* __restrict__ Wpk,
    const float* __restrict__ bf, float* __restrict__ outT,
    float* __restrict__ outS, float* __restrict__ outA, int n) {
  __shared__ short sAb[32][136];
  __shared__ float aM[2][2][16];
  __shared__ float aS[2][2][16];
  int rowBase = blockIdx.x * 32;
  stage32(A, sAb, rowBase, n, threadIdx.x);
  __syncthreads();
  int wave = threadIdx.x >> 6, lane = threadIdx.x & 63;
  int rg = wave >> 1, ch = wave & 1;
  int lr = lane & 15, lg = lane >> 4;
  int r0 = rowBase + rg * 16;
  int cb = ch * 128;
  short8 afr[4];
#pragma unroll
  for (int kk = 0; kk < 4; ++kk)
    afr[kk] = *reinterpret_cast<const short8*>(&sAb[rg * 16 + lr][kk * 32 + lg * 8]);
  f32x4 acc[8];
#pragma unroll
  for (int t = 0; t < 8; ++t) acc[t] = (f32x4){0.f, 0.f, 0.f, 0.f};
  const short8* Wp8 = reinterpret_cast<const short8*>(Wpk);
#pragma unroll
  for (int t = 0; t < 8; ++t) {
#pragma unroll
    for (int kk = 0; kk < 4; ++kk) {
      short8 bfr = Wp8[(kk * 4 + lg) * 256 + cb + t * 16 + lr];
      acc[t] = __builtin_amdgcn_mfma_f32_16x16x32_bf16(afr[kk], bfr, acc[t], 0, 0, 0);
    }
  }
  float bias_l[8];
#pragma unroll
  for (int t = 0; t < 8; ++t) bias_l[t] = bf[cb + t * 16 + lr];
  float mTr[4], mSr[4], mAr[4];
#pragma unroll
  for (int reg = 0; reg < 4; ++reg) {
    float mT = -INFINITY, mS = -INFINITY, mA = -INFINITY;
#pragma unroll
    for (int t = 0; t < 8; ++t) {
      int c = cb + t * 16 + lr;
      float val = acc[t][reg] + bias_l[t];
      acc[t][reg] = val;
      if (c < 20) mT = fmaxf(mT, val);
      else if (c < 50) mS = fmaxf(mS, val);
      else if (c < 250) mA = fmaxf(mA, val);
    }
#pragma unroll
    for (int o = 8; o; o >>= 1) {
      mT = fmaxf(mT, __shfl_xor(mT, o, 64));
      mS = fmaxf(mS, __shfl_xor(mS, o, 64));
      mA = fmaxf(mA, __shfl_xor(mA, o, 64));
    }
    mTr[reg] = mT; mSr[reg] = mS; mAr[reg] = mA;
    if (lr == 0) aM[rg][ch][lg * 4 + reg] = mA;
  }
  __syncthreads();
#pragma unroll
  for (int reg = 0; reg < 4; ++reg)
    mAr[reg] = fmaxf(mAr[reg], aM[rg][ch ^ 1][lg * 4 + reg]);
  float sTr[4], sSr[4], sAr[4];
#pragma unroll
  for (int reg = 0; reg < 4; ++reg) {
    float sT = 0.f, sS = 0.f, sA = 0.f;
#pragma unroll
    for (int t = 0; t < 8; ++t) {
      int c = cb + t * 16 + lr;
      float m = (c < 20) ? mTr[reg] : (c < 50) ? mSr[reg] : mAr[reg];
      float e = __expf(acc[t][reg] - m);
      acc[t][reg] = e;
      if (c < 20) sT += e;
      else if (c < 50) sS += e;
      else if (c < 250) sA += e;
    }
#pragma unroll
    for (int o = 8; o; o >>= 1) {
      sT += __shfl_xor(sT, o, 64);
      sS += __shfl_xor(sS, o, 64);
      sA += __shfl_xor(sA, o, 64);
    }
    sTr[reg] = sT; sSr[reg] = sS; sAr[reg] = sA;
    if (lr == 0) aS[rg][ch][lg * 4 + reg] = sA;
  }
  __syncthreads();
#pragma unroll
  for (int reg = 0; reg < 4; ++reg)
    sAr[reg] += aS[rg][ch ^ 1][lg * 4 + reg];
  int rloc = r0 + lg * 4;
#pragma unroll
  for (int reg = 0; reg < 4; ++reg) {
    int row = rloc + reg;
    if (row >= n) continue;
    float iT = 1.f / sTr[reg], iS = 1.f / sSr[reg], iA = 1.f / sAr[reg];
#pragma unroll
    for (int t = 0; t < 8; ++t) {
      int c = cb + t * 16 + lr;
      float e = acc[t][reg];
      if (c < 20) outT[(size_t)row * 20 + c] = e * iT;
      else if (c < 50) outS[(size_t)row * 30 + (c - 20)] = e * iS;
      else if (c < 250) outA[(size_t)row * 200 + (c - 50)] = e * iA;
    }
  }
}

// ---- time head: softmax(x0 @ Wtf + btf) -----------------------------------
__global__ __launch_bounds__(256) void k_time(
    const float* __restrict__ x0, const float* __restrict__ Wtf,
    const float* __restrict__ btf, float* __restrict__ outT, int n) {
  __shared__ float sW[128][16];
  __shared__ float sb[16];
  for (int t = threadIdx.x; t < 128 * 16; t += 256) {
    int k = t >> 4, j = t & 15;
    sW[k][j] = (j < 15) ? Wtf[k * 15 + j] : 0.f;
  }
  if (threadIdx.x < 16) sb[threadIdx.x] = (threadIdx.x < 15) ? btf[threadIdx.x] : 0.f;
  __syncthreads();
  int j = threadIdx.x & 15;
  int rl = threadIdx.x >> 4;
  int r = blockIdx.x * 16 + rl;
  if (r >= n) return;
  float acc = sb[j];
  const float4* xr = reinterpret_cast<const float4*>(x0 + (size_t)r * 128);
  for (int k4 = 0; k4 < 32; ++k4) {
    float4 xv = xr[k4];
    acc += xv.x * sW[k4 * 4 + 0][j] + xv.y * sW[k4 * 4 + 1][j] +
           xv.z * sW[k4 * 4 + 2][j] + xv.w * sW[k4 * 4 + 3][j];
  }
  float m = (j < 15) ? acc : -INFINITY;
#pragma unroll
  for (int o = 8; o; o >>= 1) m = fmaxf(m, __shfl_xor(m, o, 16));
  float e = (j < 15) ? __expf(acc - m) : 0.f;
  float s = e;
#pragma unroll
  for (int o = 8; o; o >>= 1) s += __shfl_xor(s, o, 16);
  if (j < 15) outT[(size_t)r * 15 + j] = e / s;
}

// ---------------------------------------------------------------------------
extern "C" void kernel_launch(void* const* d_in, const int* in_sizes, int n_in,
                              void* d_out, int out_size, void* d_ws, size_t ws_size,
                              hipStream_t stream) {
  const float* x0 = (const float*)d_in[0];
  const int* ei = (const int*)d_in[1];
  const float* W1 = (const float*)d_in[2];
  const float* b1 = (const float*)d_in[3];
  const float* Wt = (const float*)d_in[4];
  const float* bt = (const float*)d_in[5];
  const float* Ws = (const float*)d_in[6];
  const float* bs = (const float*)d_in[7];
  const float* Wa = (const float*)d_in[8];
  const float* ba = (const float*)d_in[9];
  const float* Wct = (const float*)d_in[10];
  const float* bct = (const float*)d_in[11];
  const float* Wcs = (const float*)d_in[12];
  const float* bcs = (const float*)d_in[13];
  const float* Wtf = (const float*)d_in[14];
  const float* btf = (const float*)d_in[15];
  const float* Wca = (const float*)d_in[16];
  const float* bca = (const float*)d_in[17];
  (void)n_in; (void)out_size; (void)ws_size;

  int N = in_sizes[0] / 128;
  int E = in_sizes[1] / 2;
  float* out = (float*)d_out;

  char* ws = (char*)d_ws;
  size_t off = 0;
  auto alloc = [&](size_t bytes) -> void* {
    void* p = ws + off;
    off = (off + bytes + 255) & ~(size_t)255;
    return p;
  };
  int* deg = (int*)alloc((size_t)N * 4);
  int* row_off = (int*)alloc((size_t)N * 4);
  int* bsum = (int*)alloc(256 * 4);
  int* cursor = (int*)alloc((size_t)N * 4);
  float* dinv = (float*)alloc((size_t)N * 4);
  unsigned short* csr = (unsigned short*)alloc((size_t)E * 2);
  unsigned short* WfPk = (unsigned short*)alloc((size_t)128 * 256 * 2);
  unsigned short* W1Pk = (unsigned short*)alloc((size_t)128 * 128 * 2);
  float* bf = (float*)alloc(256 * 4);
  unsigned* Yb = (unsigned*)alloc((size_t)N * 64 * 4);  // bf16 (pre-scaled x0)
  unsigned* Ab = (unsigned*)alloc((size_t)N * 64 * 4);  // bf16 (agg results)
  unsigned* Bb = (unsigned*)alloc((size_t)N * 64 * 4);  // bf16 (hidden)

  const int* srcp = ei;
  const int* dstp = ei + E;
  int gE = (E + 255) / 256;
  int gN = (N + 255) / 256;  // 196 <= 256, required by k_scan2
  int g32 = (N + 31) / 32;

  hipMemsetAsync(deg, 0, (size_t)N * 4, stream);
  k_deg<<<gE, 256, 0, stream>>>(dstp, E, deg);
  k_scan1<<<gN, 256, 0, stream>>>(deg, N, row_off, bsum);
  k_scan2<<<1, 256, 0, stream>>>(bsum, gN);
  k_finalize<<<gN, 256, 0, stream>>>(row_off, bsum, deg, cursor, dinv, N);
  k_fill<<<gE, 256, 0, stream>>>(srcp, dstp, E, cursor, csr);
  // weight packing (independent of graph work)
  k_pack128<<<64, 256, 0, stream>>>(W1, W1Pk);
  k_fuse<<<256, 128, 0, stream>>>(Wt, bt, Wct, bct, Ws, bs, Wcs, bcs, Wa, ba, Wca,
                                  bca, WfPk, bf);
  // Yb = bf16(dinv*x0) ; Ab = agg(Yb)
  k_scale<<<(N * 64 + 255) / 256, 256, 0, stream>>>(x0, dinv, Yb, N);
  k_agg<<<(N + 7) / 8, 256, 0, stream>>>(Yb, Ab, row_off, deg, csr, dinv, N);
  // Bb = bf16(dinv*relu(Ab@W1+b1))   [MFMA, col-split]
  k_mfma_gemm128<<<g32, 256, 0, stream>>>(
      (const short*)Ab, W1Pk, b1, dinv, (unsigned short*)Bb, N);
  // Ab = agg(Bb)
  k_agg<<<(N + 7) / 8, 256, 0, stream>>>(Bb, Ab, row_off, deg, csr, dinv, N);
  // heads: MFMA + fused segmented softmax  [col-split]
  k_heads_fused<<<g32, 256, 0, stream>>>(
      (const short*)Ab, WfPk, bf, out, out + (size_t)N * 20, out + (size_t)N * 65, N);
  k_time<<<(N + 15) / 16, 256, 0, stream>>>(x0, Wtf, btf, out + (size_t)N * 50, N);
}

// Round 9
// 336.831 us; speedup vs baseline: 2.0412x; 1.0100x over previous
//
#include <hip/hip_runtime.h>
#include <math.h>

// ---------------------------------------------------------------------------
// GCN forward. R8: XCD-local scatter for k_deg/k_fill (block b handles edge
// chunk b>>3 restricted to dst range b&7; assumes bid%8->XCD round-robin so
// cursor/deg/CSR lines stay in one L2 -> write-back once). k_finalize+k_scale
// fused; k_pack+k_fuse fused. Pipeline: bf16 tables, col-split MFMA GEMMs,
// fused segmented softmax, uint16 CSR.
// ---------------------------------------------------------------------------

typedef short short8 __attribute__((ext_vector_type(8)));
typedef float f32x4 __attribute__((ext_vector_type(4)));

#define FILL_CHUNK 2048

static __device__ __forceinline__ unsigned short f2bf(float x) {  // RNE
  unsigned u = __float_as_uint(x);
  u += 0x7fff + ((u >> 16) & 1);
  return (unsigned short)(u >> 16);
}
static __device__ __forceinline__ unsigned pack2bf(float lo, float hi) {
  return ((unsigned)f2bf(hi) << 16) | (unsigned)f2bf(lo);
}
static __device__ __forceinline__ float bflo(unsigned u) {
  return __uint_as_float(u << 16);
}
static __device__ __forceinline__ float bfhi(unsigned u) {
  return __uint_as_float(u & 0xffff0000u);
}

// ---- degree count, XCD-range-local ----------------------------------------
__global__ __launch_bounds__(256) void k_deg_x(
    const int* __restrict__ dst, int E, int* __restrict__ deg, int rlen) {
  int rng = blockIdx.x & 7;
  int chunk = blockIdx.x >> 3;
  int lo = rng * rlen, hi = lo + rlen;
  int base = chunk * FILL_CHUNK;
  int end = base + FILL_CHUNK;
  if (end > E) end = E;
  for (int e = base + threadIdx.x; e < end; e += 256) {
    int d = dst[e];
    if (d >= lo && d < hi) atomicAdd(&deg[d], 1);
  }
}

// ---- 3-kernel exclusive scan over N ints ----------------------------------
__global__ void k_scan1(const int* __restrict__ deg, int n,
                        int* __restrict__ excl, int* __restrict__ bsum) {
  __shared__ int sm[256];
  int i = blockIdx.x * 256 + threadIdx.x;
  int v = (i < n) ? deg[i] : 0;
  sm[threadIdx.x] = v;
  __syncthreads();
#pragma unroll
  for (int o = 1; o < 256; o <<= 1) {
    int t = (threadIdx.x >= o) ? sm[threadIdx.x - o] : 0;
    __syncthreads();
    sm[threadIdx.x] += t;
    __syncthreads();
  }
  if (i < n) excl[i] = sm[threadIdx.x] - v;
  if (threadIdx.x == 255) bsum[blockIdx.x] = sm[255];
}

__global__ void k_scan2(int* __restrict__ bsum, int nb) {
  __shared__ int sm[256];
  int v = (threadIdx.x < nb) ? bsum[threadIdx.x] : 0;
  sm[threadIdx.x] = v;
  __syncthreads();
#pragma unroll
  for (int o = 1; o < 256; o <<= 1) {
    int t = (threadIdx.x >= o) ? sm[threadIdx.x - o] : 0;
    __syncthreads();
    sm[threadIdx.x] += t;
    __syncthreads();
  }
  if (threadIdx.x < nb) bsum[threadIdx.x] = sm[threadIdx.x] - v;  // exclusive
}

// ---- fused finalize (row_off/cursor/dinv) + pre-scale x0 -> bf16 ----------
__global__ __launch_bounds__(256) void k_finscale(
    const float* __restrict__ X, const int* __restrict__ deg,
    const int* __restrict__ bsum, int* __restrict__ row_off,
    int* __restrict__ cursor, float* __restrict__ dinv,
    unsigned* __restrict__ Y, int n) {
  int p = blockIdx.x * 256 + threadIdx.x;  // pair index (2 cols)
  if (p >= n * 64) return;
  int row = p >> 6;
  float d = rsqrtf((float)(deg[row] + 1));  // +1 self-loop
  if ((p & 63) == 0) {
    int ro = row_off[row] + bsum[row >> 8];
    row_off[row] = ro;
    cursor[row] = ro;
    dinv[row] = d;
  }
  float2 v = reinterpret_cast<const float2*>(X)[p];
  Y[p] = pack2bf(v.x * d, v.y * d);
}

// ---- CSR fill (uint16), XCD-range-local ------------------------------------
__global__ __launch_bounds__(256) void k_fill_x(
    const int* __restrict__ src, const int* __restrict__ dst, int E,
    int* __restrict__ cursor, unsigned short* __restrict__ csr, int rlen) {
  int rng = blockIdx.x & 7;
  int chunk = blockIdx.x >> 3;
  int lo = rng * rlen, hi = lo + rlen;
  int base = chunk * FILL_CHUNK;
  int end = base + FILL_CHUNK;
  if (end > E) end = E;
  for (int e = base + threadIdx.x; e < end; e += 256) {
    int d = dst[e];
    if (d >= lo && d < hi) {
      int p = atomicAdd(&cursor[d], 1);
      csr[p] = (unsigned short)src[e];
    }
  }
}

// ---- aggregation on bf16 tables: out[i] = bf16(dinv[i]*(sum_s Y[s] + Y[i]))
// 2 nodes/wave: 32 lanes per node, uint2 (4 bf16 cols) per lane; fp32 accum.
__global__ __launch_bounds__(256) void k_agg(
    const unsigned* __restrict__ Y, unsigned* __restrict__ out,
    const int* __restrict__ row_off, const int* __restrict__ deg,
    const unsigned short* __restrict__ csr, const float* __restrict__ dinv,
    int n) {
  int wave = threadIdx.x >> 6;
  int lane = threadIdx.x & 63;
  int sub = lane >> 5;   // node within wave
  int sl = lane & 31;    // lane within node (uint2 index)
  int i = blockIdx.x * 8 + wave * 2 + sub;
  if (i >= n) return;
  int start = row_off[i];
  int cnt = deg[i];
  const uint2* Yv = reinterpret_cast<const uint2*>(Y);
  float a0 = 0.f, a1 = 0.f, a2 = 0.f, a3 = 0.f;
  int j = 0;
  for (; j + 3 < cnt; j += 4) {
    int s0 = csr[start + j];
    int s1 = csr[start + j + 1];
    int s2 = csr[start + j + 2];
    int s3 = csr[start + j + 3];
    uint2 u0 = Yv[(size_t)s0 * 32 + sl];
    uint2 u1 = Yv[(size_t)s1 * 32 + sl];
    uint2 u2 = Yv[(size_t)s2 * 32 + sl];
    uint2 u3 = Yv[(size_t)s3 * 32 + sl];
    a0 += (bflo(u0.x) + bflo(u1.x)) + (bflo(u2.x) + bflo(u3.x));
    a1 += (bfhi(u0.x) + bfhi(u1.x)) + (bfhi(u2.x) + bfhi(u3.x));
    a2 += (bflo(u0.y) + bflo(u1.y)) + (bflo(u2.y) + bflo(u3.y));
    a3 += (bfhi(u0.y) + bfhi(u1.y)) + (bfhi(u2.y) + bfhi(u3.y));
  }
  for (; j < cnt; ++j) {
    int s0 = csr[start + j];
    uint2 u0 = Yv[(size_t)s0 * 32 + sl];
    a0 += bflo(u0.x);
    a1 += bfhi(u0.x);
    a2 += bflo(u0.y);
    a3 += bfhi(u0.y);
  }
  uint2 us = Yv[(size_t)i * 32 + sl];
  float di = dinv[i];
  uint2 r;
  r.x = pack2bf((a0 + bflo(us.x)) * di, (a1 + bfhi(us.x)) * di);
  r.y = pack2bf((a2 + bflo(us.y)) * di, (a3 + bfhi(us.y)) * di);
  reinterpret_cast<uint2*>(out)[(size_t)i * 32 + sl] = r;
}

// ---- fused: head-weight fusion (blocks 0..255) + W1 packing (blocks 256+) -
__global__ void k_fusepack(
    const float* __restrict__ Wt, const float* __restrict__ bt,
    const float* __restrict__ Wct, const float* __restrict__ bct,
    const float* __restrict__ Ws, const float* __restrict__ bs,
    const float* __restrict__ Wcs, const float* __restrict__ bcs,
    const float* __restrict__ Wa, const float* __restrict__ ba,
    const float* __restrict__ Wca, const float* __restrict__ bca,
    unsigned short* __restrict__ WfPk, float* __restrict__ bf,
    const float* __restrict__ W1, unsigned short* __restrict__ W1Pk) {
  if (blockIdx.x >= 256) {  // pack W1 [128][128] -> [(k>>3)][col][k&7]
    int t = (blockIdx.x - 256) * 128 + threadIdx.x;  // 0..16383
    int i = t >> 7, c = t & 127;
    W1Pk[((i >> 3) * 128 + c) * 8 + (i & 7)] = f2bf(W1[t]);
    return;
  }
  int c = blockIdx.x;   // 0..255
  int i = threadIdx.x;  // 0..127
  float acc = 0.f, bacc = 0.f;
  if (c < 20) {
    for (int k = 0; k < 20; ++k) {
      float w2 = Wct[k * 20 + c];
      acc += Wt[i * 20 + k] * w2;
      bacc += bt[k] * w2;
    }
    bacc += bct[c];
  } else if (c < 50) {
    int cc = c - 20;
    for (int k = 0; k < 30; ++k) {
      float w2 = Wcs[k * 30 + cc];
      acc += Ws[i * 30 + k] * w2;
      bacc += bs[k] * w2;
    }
    bacc += bcs[cc];
  } else if (c < 250) {
    int cc = c - 50;
    for (int k = 0; k < 200; ++k) {
      float w2 = Wca[k * 200 + cc];
      acc += Wa[i * 200 + k] * w2;
      bacc += ba[k] * w2;
    }
    bacc += bca[cc];
  }
  WfPk[((i >> 3) * 256 + c) * 8 + (i & 7)] = f2bf(acc);
  if (i == 0) bf[c] = bacc;
}

// ---- stage 32 bf16 rows into LDS ------------------------------------------
static __device__ __forceinline__ void stage32(
    const short* __restrict__ A, short (*sAb)[136], int rowBase, int n, int tid) {
  for (int t = tid; t < 32 * 16; t += 256) {
    int r = t >> 4, c8 = t & 15;
    int gr = rowBase + r;
    short8 v = (short8){0, 0, 0, 0, 0, 0, 0, 0};
    if (gr < n) v = *reinterpret_cast<const short8*>(A + (size_t)gr * 128 + c8 * 8);
    *reinterpret_cast<short8*>(&sAb[r][c8 * 8]) = v;
  }
}

// ---- MFMA GEMM 128x128, col-split: wave=(rowgrp, colhalf); 16 rows x 64 cols
__global__ __launch_bounds__(256) void k_mfma_gemm128(
    const short* __restrict__ A, const unsigned short* __restrict__ Wpk,
    const float* __restrict__ bias, const float* __restrict__ dinv,
    unsigned short* __restrict__ out, int n) {
  __shared__ short sAb[32][136];
  int rowBase = blockIdx.x * 32;
  stage32(A, sAb, rowBase, n, threadIdx.x);
  __syncthreads();
  int wave = threadIdx.x >> 6, lane = threadIdx.x & 63;
  int rg = wave >> 1, ch = wave & 1;
  int lr = lane & 15, lg = lane >> 4;
  int r0 = rowBase + rg * 16;
  short8 afr[4];
#pragma unroll
  for (int kk = 0; kk < 4; ++kk)
    afr[kk] = *reinterpret_cast<const short8*>(&sAb[rg * 16 + lr][kk * 32 + lg * 8]);
  f32x4 acc[4];
#pragma unroll
  for (int t = 0; t < 4; ++t) acc[t] = (f32x4){0.f, 0.f, 0.f, 0.f};
  const short8* Wp8 = reinterpret_cast<const short8*>(Wpk);
#pragma unroll
  for (int t = 0; t < 4; ++t) {
#pragma unroll
    for (int kk = 0; kk < 4; ++kk) {
      short8 bfr = Wp8[(kk * 4 + lg) * 128 + ch * 64 + t * 16 + lr];
      acc[t] = __builtin_amdgcn_mfma_f32_16x16x32_bf16(afr[kk], bfr, acc[t], 0, 0, 0);
    }
  }
  int rloc = r0 + lg * 4;
#pragma unroll
  for (int t = 0; t < 4; ++t) {
    int col = ch * 64 + t * 16 + lr;
    float b = bias[col];
#pragma unroll
    for (int reg = 0; reg < 4; ++reg) {
      int row = rloc + reg;
      if (row < n) {
        float v = fmaxf(acc[t][reg] + b, 0.f) * dinv[row];
        out[(size_t)row * 128 + col] = f2bf(v);
      }
    }
  }
}

// ---- heads: MFMA 128x256 col-split + fused segmented softmax --------------
__global__ __launch_bounds__(256) void k_heads_fused(
    const short* __restrict__ A, const unsigned short* __restrict__ Wpk,
    const float* __restrict__ bf, float* __restrict__ outT,
    float* __restrict__ outS, float* __restrict__ outA, int n) {
  __shared__ short sAb[32][136];
  __shared__ float aM[2][2][16];
  __shared__ float aS[2][2][16];
  int rowBase = blockIdx.x * 32;
  stage32(A, sAb, rowBase, n, threadIdx.x);
  __syncthreads();
  int wave = threadIdx.x >> 6, lane = threadIdx.x & 63;
  int rg = wave >> 1, ch = wave & 1;
  int lr = lane & 15, lg = lane >> 4;
  int r0 = rowBase + rg * 16;
  int cb = ch * 128;
  short8 afr[4];
#pragma unroll
  for (int kk = 0; kk < 4; ++kk)
    afr[kk] = *reinterpret_cast<const short8*>(&sAb[rg * 16 + lr][kk * 32 + lg * 8]);
  f32x4 acc[8];
#pragma unroll
  for (int t = 0; t < 8; ++t) acc[t] = (f32x4){0.f, 0.f, 0.f, 0.f};
  const short8* Wp8 = reinterpret_cast<const short8*>(Wpk);
#pragma unroll
  for (int t = 0; t < 8; ++t) {
#pragma unroll
    for (int kk = 0; kk < 4; ++kk) {
      short8 bfr = Wp8[(kk * 4 + lg) * 256 + cb + t * 16 + lr];
      acc[t] = __builtin_amdgcn_mfma_f32_16x16x32_bf16(afr[kk], bfr, acc[t], 0, 0, 0);
    }
  }
  float bias_l[8];
#pragma unroll
  for (int t = 0; t < 8; ++t) bias_l[t] = bf[cb + t * 16 + lr];
  float mTr[4], mSr[4], mAr[4];
#pragma unroll
  for (int reg = 0; reg < 4; ++reg) {
    float mT = -INFINITY, mS = -INFINITY, mA = -INFINITY;
#pragma unroll
    for (int t = 0; t < 8; ++t) {
      int c = cb + t * 16 + lr;
      float val = acc[t][reg] + bias_l[t];
      acc[t][reg] = val;
      if (c < 20) mT = fmaxf(mT, val);
      else if (c < 50) mS = fmaxf(mS, val);
      else if (c < 250) mA = fmaxf(mA, val);
    }
#pragma unroll
    for (int o = 8; o; o >>= 1) {
      mT = fmaxf(mT, __shfl_xor(mT, o, 64));
      mS = fmaxf(mS, __shfl_xor(mS, o, 64));
      mA = fmaxf(mA, __shfl_xor(mA, o, 64));
    }
    mTr[reg] = mT; mSr[reg] = mS; mAr[reg] = mA;
    if (lr == 0) aM[rg][ch][lg * 4 + reg] = mA;
  }
  __syncthreads();
#pragma unroll
  for (int reg = 0; reg < 4; ++reg)
    mAr[reg] = fmaxf(mAr[reg], aM[rg][ch ^ 1][lg * 4 + reg]);
  float sTr[4], sSr[4], sAr[4];
#pragma unroll
  for (int reg = 0; reg < 4; ++reg) {
    float sT = 0.f, sS = 0.f, sA = 0.f;
#pragma unroll
    for (int t = 0; t < 8; ++t) {
      int c = cb + t * 16 + lr;
      float m = (c < 20) ? mTr[reg] : (c < 50) ? mSr[reg] : mAr[reg];
      float e = __expf(acc[t][reg] - m);
      acc[t][reg] = e;
      if (c < 20) sT += e;
      else if (c < 50) sS += e;
      else if (c < 250) sA += e;
    }
#pragma unroll
    for (int o = 8; o; o >>= 1) {
      sT += __shfl_xor(sT, o, 64);
      sS += __shfl_xor(sS, o, 64);
      sA += __shfl_xor(sA, o, 64);
    }
    sTr[reg] = sT; sSr[reg] = sS; sAr[reg] = sA;
    if (lr == 0) aS[rg][ch][lg * 4 + reg] = sA;
  }
  __syncthreads();
#pragma unroll
  for (int reg = 0; reg < 4; ++reg)
    sAr[reg] += aS[rg][ch ^ 1][lg * 4 + reg];
  int rloc = r0 + lg * 4;
#pragma unroll
  for (int reg = 0; reg < 4; ++reg) {
    int row = rloc + reg;
    if (row >= n) continue;
    float iT = 1.f / sTr[reg], iS = 1.f / sSr[reg], iA = 1.f / sAr[reg];
#pragma unroll
    for (int t = 0; t < 8; ++t) {
      int c = cb + t * 16 + lr;
      float e = acc[t][reg];
      if (c < 20) outT[(size_t)row * 20 + c] = e * iT;
      else if (c < 50) outS[(size_t)row * 30 + (c - 20)] = e * iS;
      else if (c < 250) outA[(size_t)row * 200 + (c - 50)] = e * iA;
    }
  }
}

// ---- time head: softmax(x0 @ Wtf + btf) -----------------------------------
__global__ __launch_bounds__(256) void k_time(
    const float* __restrict__ x0, const float* __restrict__ Wtf,
    const float* __restrict__ btf, float* __restrict__ outT, int n) {
  __shared__ float sW[128][16];
  __shared__ float sb[16];
  for (int t = threadIdx.x; t < 128 * 16; t += 256) {
    int k = t >> 4, j = t & 15;
    sW[k][j] = (j < 15) ? Wtf[k * 15 + j] : 0.f;
  }
  if (threadIdx.x < 16) sb[threadIdx.x] = (threadIdx.x < 15) ? btf[threadIdx.x] : 0.f;
  __syncthreads();
  int j = threadIdx.x & 15;
  int rl = threadIdx.x >> 4;
  int r = blockIdx.x * 16 + rl;
  if (r >= n) return;
  float acc = sb[j];
  const float4* xr = reinterpret_cast<const float4*>(x0 + (size_t)r * 128);
  for (int k4 = 0; k4 < 32; ++k4) {
    float4 xv = xr[k4];
    acc += xv.x * sW[k4 * 4 + 0][j] + xv.y * sW[k4 * 4 + 1][j] +
           xv.z * sW[k4 * 4 + 2][j] + xv.w * sW[k4 * 4 + 3][j];
  }
  float m = (j < 15) ? acc : -INFINITY;
#pragma unroll
  for (int o = 8; o; o >>= 1) m = fmaxf(m, __shfl_xor(m, o, 16));
  float e = (j < 15) ? __expf(acc - m) : 0.f;
  float s = e;
#pragma unroll
  for (int o = 8; o; o >>= 1) s += __shfl_xor(s, o, 16);
  if (j < 15) outT[(size_t)r * 15 + j] = e / s;
}

// ---------------------------------------------------------------------------
extern "C" void kernel_launch(void* const* d_in, const int* in_sizes, int n_in,
                              void* d_out, int out_size, void* d_ws, size_t ws_size,
                              hipStream_t stream) {
  const float* x0 = (const float*)d_in[0];
  const int* ei = (const int*)d_in[1];
  const float* W1 = (const float*)d_in[2];
  const float* b1 = (const float*)d_in[3];
  const float* Wt = (const float*)d_in[4];
  const float* bt = (const float*)d_in[5];
  const float* Ws = (const float*)d_in[6];
  const float* bs = (const float*)d_in[7];
  const float* Wa = (const float*)d_in[8];
  const float* ba = (const float*)d_in[9];
  const float* Wct = (const float*)d_in[10];
  const float* bct = (const float*)d_in[11];
  const float* Wcs = (const float*)d_in[12];
  const float* bcs = (const float*)d_in[13];
  const float* Wtf = (const float*)d_in[14];
  const float* btf = (const float*)d_in[15];
  const float* Wca = (const float*)d_in[16];
  const float* bca = (const float*)d_in[17];
  (void)n_in; (void)out_size; (void)ws_size;

  int N = in_sizes[0] / 128;
  int E = in_sizes[1] / 2;
  float* out = (float*)d_out;

  char* ws = (char*)d_ws;
  size_t off = 0;
  auto alloc = [&](size_t bytes) -> void* {
    void* p = ws + off;
    off = (off + bytes + 255) & ~(size_t)255;
    return p;
  };
  int* deg = (int*)alloc((size_t)N * 4);
  int* row_off = (int*)alloc((size_t)N * 4);
  int* bsum = (int*)alloc(256 * 4);
  int* cursor = (int*)alloc((size_t)N * 4);
  float* dinv = (float*)alloc((size_t)N * 4);
  unsigned short* csr = (unsigned short*)alloc((size_t)E * 2);
  unsigned short* WfPk = (unsigned short*)alloc((size_t)128 * 256 * 2);
  unsigned short* W1Pk = (unsigned short*)alloc((size_t)128 * 128 * 2);
  float* bf = (float*)alloc(256 * 4);
  unsigned* Yb = (unsigned*)alloc((size_t)N * 64 * 4);  // bf16 (pre-scaled x0)
  unsigned* Ab = (unsigned*)alloc((size_t)N * 64 * 4);  // bf16 (agg results)
  unsigned* Bb = (unsigned*)alloc((size_t)N * 64 * 4);  // bf16 (hidden)

  const int* srcp = ei;
  const int* dstp = ei + E;
  int gN = (N + 255) / 256;  // 196 <= 256, required by k_scan2
  int g32 = (N + 31) / 32;
  int rlen = (N + 7) / 8;
  int gX = 8 * ((E + FILL_CHUNK - 1) / FILL_CHUNK);

  hipMemsetAsync(deg, 0, (size_t)N * 4, stream);
  k_deg_x<<<gX, 256, 0, stream>>>(dstp, E, deg, rlen);
  k_scan1<<<gN, 256, 0, stream>>>(deg, N, row_off, bsum);
  k_scan2<<<1, 256, 0, stream>>>(bsum, gN);
  // finalize row_off/cursor/dinv + Yb = bf16(dinv*x0)
  k_finscale<<<(N * 64 + 255) / 256, 256, 0, stream>>>(
      x0, deg, bsum, row_off, cursor, dinv, Yb, N);
  k_fill_x<<<gX, 256, 0, stream>>>(srcp, dstp, E, cursor, csr, rlen);
  // weight packing + head fusion (independent of graph work)
  k_fusepack<<<384, 128, 0, stream>>>(Wt, bt, Wct, bct, Ws, bs, Wcs, bcs, Wa, ba,
                                      Wca, bca, WfPk, bf, W1, W1Pk);
  // Ab = agg(Yb)
  k_agg<<<(N + 7) / 8, 256, 0, stream>>>(Yb, Ab, row_off, deg, csr, dinv, N);
  // Bb = bf16(dinv*relu(Ab@W1+b1))   [MFMA, col-split]
  k_mfma_gemm128<<<g32, 256, 0, stream>>>(
      (const short*)Ab, W1Pk, b1, dinv, (unsigned short*)Bb, N);
  // Ab = agg(Bb)
  k_agg<<<(N + 7) / 8, 256, 0, stream>>>(Bb, Ab, row_off, deg, csr, dinv, N);
  // heads: MFMA + fused segmented softmax  [col-split]
  k_heads_fused<<<g32, 256, 0, stream>>>(
      (const short*)Ab, WfPk, bf, out, out + (size_t)N * 20, out + (size_t)N * 65, N);
  k_time<<<(N + 15) / 16, 256, 0, stream>>>(x0, Wtf, btf, out + (size_t)N * 50, N);
}